// Round 20
// baseline (162.480 us; speedup 1.0000x reference)
//
#include <hip/hip_runtime.h>

#define BT 4096      // B*T
#define Dd 1024
#define Tt 2048
#define ATT_SCALE 0.18033688f  // 0.125 * log2(e)

typedef __attribute__((ext_vector_type(8))) short bf16x8;
typedef __attribute__((ext_vector_type(4))) float f32x4;
typedef __attribute__((ext_vector_type(4))) unsigned u32x4;

__device__ __forceinline__ short f2bf(float f) {
  unsigned u = __builtin_bit_cast(unsigned, f);
  u = (u + 0x7FFFu + ((u >> 16) & 1u)) >> 16;
  return (short)u;
}
__device__ __forceinline__ float bf2f(short s) {
  unsigned u = ((unsigned)(unsigned short)s) << 16;
  return __builtin_bit_cast(float, u);
}
__device__ __forceinline__ unsigned cvt_pk_bf16(float a, float b) {
  unsigned r;
  asm("v_cvt_pk_bf16_f32 %0, %1, %2" : "=v"(r) : "v"(a), "v"(b));
  return r;
}

__device__ __forceinline__ void load_lds16(const void* gsrc, void* ldst) {
  __builtin_amdgcn_global_load_lds(
      (const __attribute__((address_space(1))) void*)gsrc,
      (__attribute__((address_space(3))) void*)ldst, 16, 0, 0);
}

// --- merged prep: weight transposes (sections 0..1359) + x fp32->bf16 (1360..5455) --
__global__ __launch_bounds__(256) void k_wtall(
    const float* __restrict__ qkv_w, const float* __restrict__ memv_w,
    const float* __restrict__ out_w, const float* __restrict__ w1w,
    const float* __restrict__ w2w, const float* __restrict__ w1r,
    const float* __restrict__ w2r, const float* __restrict__ memg_w,
    short* __restrict__ WTall, short* __restrict__ WTout,
    const float* __restrict__ x, short* __restrict__ xb) {
  __shared__ float tile[64][65];
  const int bid = blockIdx.x;
  if (bid >= 1360) {  // cvt section: 4096 blocks x 256 float4
    int i = (bid - 1360) * 256 + threadIdx.x;
    float4 v = ((const float4*)x)[i];
    short4 o;
    o.x = f2bf(v.x); o.y = f2bf(v.y); o.z = f2bf(v.z); o.w = f2bf(v.w);
    ((short4*)xb)[i] = o;
    return;
  }
  const float* src;
  short* dst;
  int N, n0, k0, rowoff;
  if (bid < 768) {
    src = qkv_w; dst = WTall; N = 3072;
    n0 = (bid % 48) * 64; k0 = (bid / 48) * 64; rowoff = 0;
  } else if (bid < 1024) {
    int r = bid - 768;
    src = memv_w; dst = WTall; N = 1024;
    n0 = (r % 16) * 64; k0 = (r / 16) * 64; rowoff = 3072;
  } else if (bid < 1280) {
    int r = bid - 1024;
    src = out_w; dst = WTout; N = 1024;
    n0 = (r % 16) * 64; k0 = (r / 16) * 64; rowoff = 0;
  } else {
    int r = bid - 1280;
    int z = r / 16;
    src = z == 0 ? w1w : z == 1 ? w2w : z == 2 ? w1r : z == 3 ? w2r : memg_w;
    dst = WTall; N = (z == 4) ? 16 : 64;
    n0 = 0; k0 = (r % 16) * 64; rowoff = 4096 + z * 64;
  }
  const int c = threadIdx.x & 63, r4 = threadIdx.x >> 6;
#pragma unroll
  for (int i = 0; i < 16; ++i) {
    int r = i * 4 + r4;
    float v = 0.f;
    if (n0 + c < N) v = src[(size_t)(k0 + r) * N + n0 + c];
    tile[r][c] = v;
  }
  __syncthreads();
#pragma unroll
  for (int i = 0; i < 16; ++i) {
    int n = i * 4 + r4;
    if (n0 + n < N)
      dst[(size_t)(rowoff + n0 + n) * 1024 + k0 + c] = f2bf(tile[c][n]);
  }
}

// ====== 128x128 GEMM, BK=32 dbuf (32KB -> 4 blocks/CU), counted-vmcnt schedule =====
// q-range outputs are pre-scaled by ATT_SCALE (folds attention's softmax scale).
__global__ __launch_bounds__(256, 4) void k_g128(
    const short* __restrict__ A, const short* __restrict__ Bt,
    const float* __restrict__ bias, const float* __restrict__ bias2,
    short* __restrict__ oq, short* __restrict__ ok_, short* __restrict__ ov,
    short* __restrict__ omv, float* __restrict__ ocs, int K) {
  __shared__ __align__(16) short lds[16384];  // 32 KiB
  const int tid = threadIdx.x;
  const int wid = tid >> 6, lane = tid & 63;
  const int wr = wid >> 1, wc = wid & 1;
  const int ql = lane & 15, g = lane >> 4;
  int wg = blockIdx.x, xcd = wg & 7, idx = wg >> 3;
  const int n_t = idx >> 2;
  const int m_t = xcd * 4 + (idx & 3);
  const int nkt = K >> 5;
  const int bm = m_t * 128, bn = n_t * 128;
  f32x4 acc[4][4] = {};

  const short* srcA[2];
  const short* srcB[2];
  short* dstA[2];
  short* dstB[2];
#pragma unroll
  for (int j = 0; j < 2; ++j) {
    int o16 = j * 256 + tid;
    int rr = o16 >> 2, u = o16 & 3;
    int sp = u ^ ((rr >> 1) & 3);
    srcA[j] = A + (size_t)(bm + rr) * K + sp * 8;
    srcB[j] = Bt + (size_t)(bn + rr) * K + sp * 8;
    dstA[j] = lds + o16 * 8;
    dstB[j] = lds + 8192 + o16 * 8;
  }
#define STG(D, KT)                                                            \
  do {                                                                        \
    const int k0s = (KT) << 5;                                                \
    _Pragma("unroll") for (int j = 0; j < 2; ++j) {                           \
      load_lds16(srcA[j] + k0s, dstA[j] + (D)*4096);                          \
      load_lds16(srcB[j] + k0s, dstB[j] + (D)*4096);                          \
    }                                                                         \
  } while (0)

  const int sw = (g ^ ((ql >> 1) & 3)) << 4;
  const char* bA = (const char*)lds + wr * 4096 + ql * 64 + sw;
  const char* bB = (const char*)lds + 16384 + wc * 4096 + ql * 64 + sw;

#define RD_A(DST, DOFF, MQ)                                                    \
  _Pragma("unroll") for (int mi = 0; mi < 2; ++mi)                             \
      DST[mi] = *(const bf16x8*)(bA + (DOFF) + (MQ)*2048 + mi * 1024);
#define RD_B(DST, DOFF, NQ)                                                    \
  _Pragma("unroll") for (int ni = 0; ni < 2; ++ni)                             \
      DST[ni] = *(const bf16x8*)(bB + (DOFF) + (NQ)*2048 + ni * 1024);
#define MFMA4(AF, BF, MQ, NQ)                                                  \
  _Pragma("unroll") for (int mi = 0; mi < 2; ++mi)                             \
      _Pragma("unroll") for (int ni = 0; ni < 2; ++ni)                         \
          acc[(MQ)*2 + mi][(NQ)*2 + ni] =                                      \
      __builtin_amdgcn_mfma_f32_16x16x32_bf16(                                 \
          BF[ni], AF[mi], acc[(MQ)*2 + mi][(NQ)*2 + ni], 0, 0, 0)

  STG(0, 0);

  for (int kt = 0; kt < nkt; ++kt) {
    const int d = kt & 1;
    const int dOff = d << 13;
    const bool s1 = kt + 1 < nkt;
    if (s1) {
      STG(d ^ 1, kt + 1);
      asm volatile("s_waitcnt vmcnt(4)" ::: "memory");
    } else {
      asm volatile("s_waitcnt vmcnt(0)" ::: "memory");
    }
    __builtin_amdgcn_sched_barrier(0);
    __builtin_amdgcn_s_barrier();
    bf16x8 a0[2], a1[2], b0[2], b1[2];
    RD_A(a0, dOff, 0);
    RD_A(a1, dOff, 1);
    RD_B(b0, dOff, 0);
    RD_B(b1, dOff, 1);
    asm volatile("s_waitcnt lgkmcnt(0)" ::: "memory");
    __builtin_amdgcn_sched_barrier(0);
    __builtin_amdgcn_s_setprio(1);
    MFMA4(a0, b0, 0, 0);
    MFMA4(a0, b1, 0, 1);
    MFMA4(a1, b1, 1, 1);
    MFMA4(a1, b0, 1, 0);
    __builtin_amdgcn_s_setprio(0);
    __builtin_amdgcn_sched_barrier(0);
    __builtin_amdgcn_s_barrier();
    __builtin_amdgcn_sched_barrier(0);
  }
#undef MFMA4
#undef RD_A
#undef RD_B
#undef STG

#pragma unroll
  for (int a = 0; a < 4; ++a) {
    const int m = bm + wr * 64 + a * 16 + ql;
    const int b = m >> 11, t = m & 2047;
#pragma unroll
    for (int c = 0; c < 4; ++c) {
      const int n0 = bn + wc * 64 + c * 16 + g * 4;
      f32x4 v = acc[a][c];
      if (n0 < 3072) {
        const float4 b4 = *(const float4*)&bias[n0];
        v[0] += b4.x; v[1] += b4.y; v[2] += b4.z; v[3] += b4.w;
        const int sel = n0 >> 10, rem = n0 & 1023;
        if (sel == 0) {
          v[0] *= ATT_SCALE; v[1] *= ATT_SCALE; v[2] *= ATT_SCALE; v[3] *= ATT_SCALE;
          uint2 pk = make_uint2(cvt_pk_bf16(v[0], v[1]), cvt_pk_bf16(v[2], v[3]));
          *(uint2*)&oq[((size_t)(b * 16 + (rem >> 6)) * 2048 + t) * 64 + (rem & 63)] = pk;
        } else if (sel == 1) {
          uint2 pk = make_uint2(cvt_pk_bf16(v[0], v[1]), cvt_pk_bf16(v[2], v[3]));
          *(uint2*)&ok_[((size_t)(b * 16 + (rem >> 6)) * 2048 + t) * 64 + (rem & 63)] = pk;
        } else {
          uint2 pk = make_uint2(cvt_pk_bf16(v[0], v[1]), cvt_pk_bf16(v[2], v[3]));
          *(uint2*)&ov[(size_t)(b * 2048 + t) * 1024 + rem] = pk;
        }
      } else if (n0 < 4096) {
        const float4 b4 = *(const float4*)&bias2[n0 - 3072];
        v[0] += b4.x; v[1] += b4.y; v[2] += b4.z; v[3] += b4.w;
        uint2 pk = make_uint2(cvt_pk_bf16(v[0], v[1]), cvt_pk_bf16(v[2], v[3]));
        *(uint2*)&omv[(size_t)(b * 2048 + t) * 1024 + n0 - 3072] = pk;
      } else if (n0 < 4368) {
        *(f32x4*)&ocs[(size_t)(b * 2048 + t) * 272 + n0 - 4096] = v;
      }
    }
  }
}

// ====== out-GEMM: 64x64, BK=32 dbuf (16KB), counted vmcnt(2), grid 1024 (4/CU) =====
__global__ __launch_bounds__(256, 4) void k_gout(
    const short* __restrict__ A, const short* __restrict__ Bt,
    const float* __restrict__ bias, float* __restrict__ C, int K) {
  __shared__ __align__(16) short lds[8192];  // 16 KiB
  const int tid = threadIdx.x;
  const int wid = tid >> 6, lane = tid & 63;
  const int wr = wid >> 1, wc = wid & 1;
  const int ql = lane & 15, g = lane >> 4;
  int wg = blockIdx.x, xcd = wg & 7, idx = wg >> 3;
  const int n_t = idx >> 3, m_t = xcd * 8 + (idx & 7);
  const int bm = m_t * 64, bn = n_t * 64;
  const int nkt = K >> 5;
  f32x4 acc[2][2] = {};

  const short* srcA;
  const short* srcB;
  short* dstA;
  short* dstB;
  {
    int rr = tid >> 2, u = tid & 3;
    int sp = u ^ ((rr >> 1) & 3);
    srcA = A + (size_t)(bm + rr) * K + sp * 8;
    srcB = Bt + (size_t)(bn + rr) * K + sp * 8;
    dstA = lds + tid * 8;
    dstB = lds + 4096 + tid * 8;
  }
#define STG(D, KT)                                                            \
  do {                                                                        \
    const int k0s = (KT) << 5;                                                \
    load_lds16(srcA + k0s, dstA + (D)*2048);                                  \
    load_lds16(srcB + k0s, dstB + (D)*2048);                                  \
  } while (0)

  const int sw = (g ^ ((ql >> 1) & 3)) << 4;
  const char* bA = (const char*)lds + wr * 2048 + ql * 64 + sw;
  const char* bB = (const char*)lds + 8192 + wc * 2048 + ql * 64 + sw;

  STG(0, 0);

  for (int kt = 0; kt < nkt; ++kt) {
    const int d = kt & 1;
    const int dOff = d << 12;
    const bool s1 = kt + 1 < nkt;
    if (s1) {
      STG(d ^ 1, kt + 1);
      asm volatile("s_waitcnt vmcnt(2)" ::: "memory");
    } else {
      asm volatile("s_waitcnt vmcnt(0)" ::: "memory");
    }
    __builtin_amdgcn_sched_barrier(0);
    __builtin_amdgcn_s_barrier();
    bf16x8 af[2], bf2[2];
#pragma unroll
    for (int mi = 0; mi < 2; ++mi)
      af[mi] = *(const bf16x8*)(bA + dOff + mi * 1024);
#pragma unroll
    for (int ni = 0; ni < 2; ++ni)
      bf2[ni] = *(const bf16x8*)(bB + dOff + ni * 1024);
    asm volatile("s_waitcnt lgkmcnt(0)" ::: "memory");
    __builtin_amdgcn_sched_barrier(0);
    __builtin_amdgcn_s_setprio(1);
#pragma unroll
    for (int mi = 0; mi < 2; ++mi)
#pragma unroll
      for (int ni = 0; ni < 2; ++ni)
        acc[mi][ni] = __builtin_amdgcn_mfma_f32_16x16x32_bf16(
            bf2[ni], af[mi], acc[mi][ni], 0, 0, 0);
    __builtin_amdgcn_s_setprio(0);
    __builtin_amdgcn_sched_barrier(0);
    __builtin_amdgcn_s_barrier();
    __builtin_amdgcn_sched_barrier(0);
  }
#undef STG

#pragma unroll
  for (int a = 0; a < 2; ++a) {
    const int m = bm + wr * 32 + a * 16 + ql;
#pragma unroll
    for (int c = 0; c < 2; ++c) {
      const int n0 = bn + wc * 32 + c * 16 + g * 4;
      f32x4 v = acc[a][c];
      const float4 b4 = *(const float4*)&bias[n0];
      v[0] += b4.x; v[1] += b4.y; v[2] += b4.z; v[3] += b4.w;
      *(f32x4*)&C[(size_t)m * 1024 + n0] = v;
    }
  }
}

// -------- merged: Plücker lines (bid<256) || V transpose (bid>=256) -----------------
__global__ __launch_bounds__(256) void k_lv(const float* __restrict__ Cs,
                                            const float* __restrict__ Jm,
                                            float* __restrict__ u,
                                            float* __restrict__ rr,
                                            const short* __restrict__ vtmp,
                                            short* __restrict__ vb) {
  __shared__ short tile[64][68];
  const int bid = blockIdx.x;
  if (bid >= 256) {  // vtrans section: 1024 blocks
    const int r2 = bid - 256;
    const int bh = r2 >> 5, b = bh >> 4, h = bh & 15;
    const int t0 = (r2 & 31) * 64;
    const int tid = threadIdx.x;
#pragma unroll
    for (int pass = 0; pass < 16; ++pass) {
      int r = pass * 4 + (tid >> 6);
      int c = tid & 63;
      tile[r][c] = vtmp[((size_t)(b * 2048) + t0 + r) * 1024 + h * 64 + c];
    }
    __syncthreads();
#pragma unroll
    for (int pass = 0; pass < 16; ++pass) {
      int r = pass * 4 + (tid >> 6);
      int c = tid & 63;
      int cp = (c & 32) | (((c >> 2) & 3) << 3) | (((c >> 4) & 1) << 2) | (c & 3);
      vb[(((size_t)b * 16 + h) * 64 + r) * 2048 + t0 + cp] = tile[c][r];
    }
    return;
  }
  int idx = bid * 256 + threadIdx.x;  // [0, 65536)
  int h = idx & 15, t = (idx >> 4) & 2047, b = idx >> 15;
  const float* rowx = Cs + (size_t)(b * 2048 + t) * 272;
  float w1[4], w2[4], r1[4], r2v[4];
  if (t == 0) {
#pragma unroll
    for (int i = 0; i < 4; ++i) w1[i] = 0.f;
  } else {
    const float* prev = Cs + (size_t)(b * 2048 + t - 1) * 272;
#pragma unroll
    for (int i = 0; i < 4; ++i) w1[i] = prev[h * 4 + i];
  }
#pragma unroll
  for (int i = 0; i < 4; ++i) {
    w2[i] = rowx[64 + h * 4 + i];
    r1[i] = rowx[128 + h * 4 + i];
    r2v[i] = rowx[192 + h * 4 + i];
  }
  const int pi[6] = {0, 0, 0, 1, 1, 2}, pj[6] = {1, 2, 3, 2, 3, 3};
  float wl[6], rl[6], nw = 0.f, nr = 0.f;
#pragma unroll
  for (int e = 0; e < 6; ++e) {
    wl[e] = w1[pi[e]] * w2[pj[e]] - w1[pj[e]] * w2[pi[e]];
    rl[e] = r1[pi[e]] * r2v[pj[e]] - r1[pj[e]] * r2v[pi[e]];
    nw += wl[e] * wl[e];
    nr += rl[e] * rl[e];
  }
  nw = 1.f / fmaxf(sqrtf(nw), 1e-12f);
  nr = 1.f / fmaxf(sqrtf(nr), 1e-12f);
  size_t base = (((size_t)b * 16 + h) * 2048 + t) * 6;
#pragma unroll
  for (int jc = 0; jc < 6; ++jc) {
    float s = 0.f;
#pragma unroll
    for (int i = 0; i < 6; ++i) s += wl[i] * Jm[i * 6 + jc];
    u[base + jc] = s * nw;
    rr[base + jc] = rl[jc] * nr;
  }
}

// ---------------- causal flash attention, swapped-operand, UNPAIRED ----------------
// q pre-scaled in GEMM epilogue; exact defer-rescale via __any.
__device__ __forceinline__ void attn_core(const bf16x8 qa[2], f32x4 o[4],
                                          float& m, float& l,
                                          const short* __restrict__ Kc,
                                          const short* __restrict__ Vc,
                                          int qt, int kt, int qglob,
                                          int ql, int g) {
  const int kv0 = kt * 64;
  f32x4 s4[4];
  __builtin_amdgcn_s_setprio(1);
#pragma unroll
  for (int nt = 0; nt < 4; ++nt) {
    int krow = nt * 16 + ql;
    f32x4 s = {0.f, 0.f, 0.f, 0.f};
#pragma unroll
    for (int kc = 0; kc < 2; ++kc) {
      int sl = (kc * 4 + g) ^ (krow & 7);
      bf16x8 af = *(const bf16x8*)&Kc[krow * 64 + sl * 8];
      s = __builtin_amdgcn_mfma_f32_16x16x32_bf16(af, qa[kc], s, 0, 0, 0);
    }
    s4[nt] = s;
  }
  __builtin_amdgcn_s_setprio(0);
  float mt = -1e30f;
  const bool diag = (kt == qt);
#pragma unroll
  for (int nt = 0; nt < 4; ++nt)
#pragma unroll
    for (int rg = 0; rg < 4; ++rg) {
      float v = s4[nt][rg];
      if (diag) {
        int kk = kv0 + nt * 16 + g * 4 + rg;
        v = (kk <= qglob) ? v : -1e30f;
      }
      s4[nt][rg] = v;
      mt = fmaxf(mt, v);
    }
  mt = fmaxf(mt, __shfl_xor(mt, 16, 64));
  mt = fmaxf(mt, __shfl_xor(mt, 32, 64));
  float mnew = fmaxf(m, mt);
  if (__any(mnew > m)) {  // exact: skip only when sf==1 for all lanes
    float sf = __builtin_amdgcn_exp2f(m - mnew);
    m = mnew;
    l *= sf;
#pragma unroll
    for (int nt = 0; nt < 4; ++nt) o[nt] *= sf;
  }
  float rs = 0.f;
#pragma unroll
  for (int nt = 0; nt < 4; ++nt)
#pragma unroll
    for (int rg = 0; rg < 4; ++rg) {
      float p = __builtin_amdgcn_exp2f(s4[nt][rg] - m);
      s4[nt][rg] = p;
      rs += p;
    }
  rs += __shfl_xor(rs, 16, 64);
  rs += __shfl_xor(rs, 32, 64);
  l += rs;
  bf16x8 pf[2];
#pragma unroll
  for (int kc = 0; kc < 2; ++kc) {
    u32x4 w;
    w[0] = cvt_pk_bf16(s4[2 * kc][0], s4[2 * kc][1]);
    w[1] = cvt_pk_bf16(s4[2 * kc][2], s4[2 * kc][3]);
    w[2] = cvt_pk_bf16(s4[2 * kc + 1][0], s4[2 * kc + 1][1]);
    w[3] = cvt_pk_bf16(s4[2 * kc + 1][2], s4[2 * kc + 1][3]);
    pf[kc] = __builtin_bit_cast(bf16x8, w);
  }
  __builtin_amdgcn_s_setprio(1);
#pragma unroll
  for (int nt2 = 0; nt2 < 4; ++nt2) {
    int d = nt2 * 16 + ql;
#pragma unroll
    for (int kc = 0; kc < 2; ++kc) {
      int sl = (kc * 4 + g) ^ (d & 7);
      bf16x8 vf = *(const bf16x8*)&Vc[d * 64 + sl * 8];
      o[nt2] = __builtin_amdgcn_mfma_f32_16x16x32_bf16(vf, pf[kc], o[nt2], 0, 0, 0);
    }
  }
  __builtin_amdgcn_s_setprio(0);
}

// epilogue with fused gmean*memval: Fb = bf16(o/l + gm*mvb)
__device__ __forceinline__ void attn_epi(const f32x4 o[4], float l,
                                         short* __restrict__ Fb,
                                         const short* __restrict__ mvb,
                                         const float* __restrict__ gm,
                                         float* ep,
                                         int b, int h, int qt, int wave, int lane) {
  const int ql = lane & 15, g = lane >> 4;
  float inv = 1.f / l;
#pragma unroll
  for (int nt2 = 0; nt2 < 4; ++nt2) {
    f32x4 v = o[nt2] * inv;
    *(f32x4*)&ep[ql * 64 + (((nt2 * 4 + g) ^ (ql & 7)) << 2)] = v;
  }
  const size_t rowbase = ((size_t)b * 2048 + qt * 64 + wave * 16);
  short* srow = Fb + rowbase * 1024 + h * 64;
  const short* mrow = mvb + rowbase * 1024 + h * 64;
  const float* grow = gm + rowbase;
#pragma unroll
  for (int p = 0; p < 8; ++p) {
    int prow = p * 2 + (lane >> 5);
    int d2 = (lane & 31) * 2;
    const float* rp = &ep[prow * 64 + (((d2 >> 2) ^ (prow & 7)) << 2) + (d2 & 3)];
    float2 vv = *(const float2*)rp;
    float gg = grow[prow];
    unsigned mvp = *(const unsigned*)&mrow[(size_t)prow * 1024 + d2];
    float m0 = bf2f((short)(mvp & 0xffff));
    float m1 = bf2f((short)(mvp >> 16));
    *(unsigned*)&srow[(size_t)prow * 1024 + d2] =
        cvt_pk_bf16(vv.x + gg * m0, vv.y + gg * m1);
  }
}

__global__ __launch_bounds__(256, 4) void k_attn(const short* __restrict__ Q,
                                                 const short* __restrict__ Kg,
                                                 const short* __restrict__ Vg,
                                                 const short* __restrict__ mvb,
                                                 const float* __restrict__ gm,
                                                 short* __restrict__ Fb) {
  __shared__ short Kt[2][64 * 64];  // 16KB
  __shared__ short Vt[2][64 * 64];  // 16KB
  const int wg = blockIdx.x;                 // 1024 blocks
  const int x = wg & 7, r = wg >> 3;         // XCD x owns bh in {4x..4x+3}
  const int q = r >> 2, j = r & 3;           // quad-balanced (bh, qt)
  const int bh = 4 * x + j;
  const int q2 = (q + 16) & 31;
  const int qt = (j == 0) ? q : (j == 1) ? 31 - q : (j == 2) ? q2 : 31 - q2;
  const int b = bh >> 4, h = bh & 15;
  const int tid = threadIdx.x;
  const int wave = tid >> 6, lane = tid & 63;
  const int ql = lane & 15, g = lane >> 4;
  const int qglob = qt * 64 + wave * 16 + ql;
  const short* qr = Q + ((size_t)bh * 2048 + qglob) * 64;
  bf16x8 qa[2];
  qa[0] = *(const bf16x8*)&qr[g * 8];
  qa[1] = *(const bf16x8*)&qr[32 + g * 8];
  f32x4 o[4] = {};
  float m = -1e30f, l = 0.f;
  const short* kgb = Kg + (size_t)bh * 2048 * 64;
  const short* vgb = Vg + (size_t)bh * 64 * 2048;

  auto stage = [&](int buf, int kt) {
    int kv0 = kt * 64;
#pragma unroll
    for (int jj = 0; jj < 2; ++jj) {
      int slot = (wave * 2 + jj) * 64 + lane;
      int rr = slot >> 3, s8 = slot & 7;
      int ss = s8 ^ (rr & 7);
      load_lds16(kgb + (size_t)(kv0 + rr) * 64 + ss * 8, &Kt[buf][slot * 8]);
      load_lds16(vgb + (size_t)rr * 2048 + kv0 + ss * 8, &Vt[buf][slot * 8]);
    }
  };

  stage(0, 0);
  int cur = 0;
  for (int it = 0; it <= qt; ++it) {
    __syncthreads();
    if (it < qt) stage(cur ^ 1, it + 1);
    attn_core(qa, o, m, l, Kt[cur], Vt[cur], qt, it, qglob, ql, g);
    cur ^= 1;
  }
  __syncthreads();
  float* ep = (float*)&Kt[0][0] + wave * 1024;  // 16KB scratch across Kt
  attn_epi(o, l, Fb, mvb, gm, ep, b, h, qt, wave, lane);
}

// ------------- decayed prefix scan per channel: w[bh][ch][t] = S_t[p][q] -------------
__global__ __launch_bounds__(256) void k_scanw(const float* __restrict__ u,
                                               float* __restrict__ w,
                                               const float* __restrict__ decays) {
  __shared__ float wtot[4];
  const int ch = blockIdx.x;
  const int bh = blockIdx.y;
  const float d = decays[bh & 15];
  const int p = ch / 6, q = ch % 6;
  const int tid = threadIdx.x, lane = tid & 63, wv = tid >> 6;
  const float* ub = u + (size_t)bh * 2048 * 6;
  const int t0 = tid * 8;
  float z[8];
  float a = 0.f;
#pragma unroll
  for (int i = 0; i < 8; ++i) {
    float up = ub[(t0 + i) * 6 + p], uq = ub[(t0 + i) * 6 + q];
    z[i] = up * uq;
    a = d * (a + z[i]);
  }
  float d8 = d * d; d8 *= d8; d8 *= d8;
  float I = a;
  float ds = d8;
#pragma unroll
  for (int s = 1; s < 64; s <<= 1) {
    float v = __shfl_up(I, s, 64);
    if (lane >= s) I += ds * v;
    ds *= ds;
  }
  if (lane == 63) wtot[wv] = I;
  __syncthreads();
  float carry = 0.f;
  for (int w2 = 0; w2 < wv; ++w2) carry = carry * ds + wtot[w2];
  float dlp1 = exp2f(log2f(d8) * (float)(lane + 1));
  float Ig = I + dlp1 * carry;
  float E = __shfl_up(Ig, 1, 64);
  if (lane == 0) E = carry;
  float S = E;
  float out[8];
#pragma unroll
  for (int i = 0; i < 8; ++i) {
    out[i] = S;
    S = d * (S + z[i]);
  }
  float4* wp = (float4*)(w + ((size_t)bh * 36 + ch) * 2048 + t0);
  wp[0] = make_float4(out[0], out[1], out[2], out[3]);
  wp[1] = make_float4(out[4], out[5], out[6], out[7]);
}

// ---- fused scandot+gate: gmean[b,t] = mean_h sig(score_h*scale_h)*sig(memg_h) -----
__global__ __launch_bounds__(128) void k_sg(const float* __restrict__ rr,
                                            const float* __restrict__ w,
                                            const float* __restrict__ Cs,
                                            const float* __restrict__ memg_b,
                                            const float* __restrict__ mem_scale,
                                            float* __restrict__ gmean) {
  int idx = blockIdx.x * 128 + threadIdx.x;  // 32 blocks x 128 = 4096
  int b = idx >> 11, t = idx & 2047;
  float acc = 0.f;
#pragma unroll 1
  for (int h = 0; h < 16; ++h) {
    const int bh = b * 16 + h;
    const float* rb = rr + ((size_t)bh * 2048 + t) * 6;
    float r[6];
#pragma unroll
    for (int i = 0; i < 6; ++i) r[i] = rb[i];
    const float* wb = w + (size_t)bh * 36 * 2048 + t;
    float s = 0.f;
#pragma unroll
    for (int ch = 0; ch < 36; ++ch)
      s += r[ch / 6] * r[ch % 6] * wb[(size_t)ch * 2048];
    float gl = Cs[(size_t)idx * 272 + 256 + h] + memg_b[h];
    float a = 1.f / (1.f + __expf(-s * mem_scale[h]));
    float gg = 1.f / (1.f + __expf(-gl));
    acc += a * gg;
  }
  gmean[idx] = acc * (1.f / 16.f);
}

extern "C" void kernel_launch(void* const* d_in, const int* in_sizes, int n_in,
                              void* d_out, int out_size, void* d_ws, size_t ws_size,
                              hipStream_t stream) {
  const float* x = (const float*)d_in[0];
  const float* qkv_w = (const float*)d_in[1];
  const float* qkv_b = (const float*)d_in[2];
  const float* w1w = (const float*)d_in[3];
  const float* w2w = (const float*)d_in[4];
  const float* w1r = (const float*)d_in[5];
  const float* w2r = (const float*)d_in[6];
  const float* memv_w = (const float*)d_in[7];
  const float* memv_b = (const float*)d_in[8];
  const float* memg_w = (const float*)d_in[9];
  const float* memg_b = (const float*)d_in[10];
  const float* mem_scale = (const float*)d_in[11];
  const float* out_w = (const float*)d_in[12];
  const float* out_b = (const float*)d_in[13];
  const float* Jm = (const float*)d_in[14];
  const float* decays = (const float*)d_in[15];

  char* w = (char*)d_ws;
  size_t off = 0;
  auto alloc = [&](size_t bytes) -> void* {
    void* p = w + off;
    off += (bytes + 255) & ~(size_t)255;
    return p;
  };
  short* xb = (short*)alloc((size_t)BT * Dd * 2);
  short* WTall = (short*)alloc((size_t)4480 * 1024 * 2);  // qkv|memv|sm
  short* WTout = (short*)alloc((size_t)1024 * 1024 * 2);
  short* qb = (short*)alloc((size_t)32 * 2048 * 64 * 2);
  short* kb = (short*)alloc((size_t)32 * 2048 * 64 * 2);
  short* vtmp = (short*)alloc((size_t)BT * 1024 * 2);
  short* vb = (short*)alloc((size_t)32 * 64 * 2048 * 2);
  float* Csm = (float*)alloc((size_t)BT * 272 * 4);
  float* ua = (float*)alloc((size_t)32 * 2048 * 6 * 4);
  float* ra = (float*)alloc((size_t)32 * 2048 * 6 * 4);
  float* gm = (float*)alloc((size_t)BT * 4);
  short* mvb = (short*)alloc((size_t)BT * 1024 * 2);
  short* Fb = (short*)alloc((size_t)BT * Dd * 2);
  float* wscan = (float*)alloc((size_t)32 * 36 * 2048 * 4);
  (void)ws_size; (void)in_sizes; (void)n_in; (void)out_size;

  // prep: all weight transposes + x->bf16 in ONE launch
  k_wtall<<<5456, 256, 0, stream>>>(qkv_w, memv_w, out_w, w1w, w2w, w1r, w2r,
                                    memg_w, WTall, WTout, x, xb);

  // fused GEMM: qkv (q pre-scaled) | memv->bf16 | sm->Csm over N=4480, 4 blocks/CU
  k_g128<<<1120, 256, 0, stream>>>(xb, WTall, qkv_b, memv_b,
                                   qb, kb, vtmp, mvb, Csm, 1024);

  // lines (256 blocks) || vtrans (1024 blocks) in one launch
  k_lv<<<1280, 256, 0, stream>>>(Csm, Jm, ua, ra, vtmp, vb);

  // decay scan + fused scandot/gate
  k_scanw<<<dim3(36, 32), 256, 0, stream>>>(ua, wscan, decays);
  k_sg<<<32, 128, 0, stream>>>(ra, wscan, Csm, memg_b, mem_scale, gm);

  // attention (epilogue fuses + gm*mvb -> Fb): 1024 blocks, 4/CU, quad-balanced
  k_attn<<<1024, 256, 0, stream>>>(qb, kb, vb, mvb, gm, Fb);

  // final GEMM: 64x64-tile full-K, fp32 + bias -> d_out, grid 1024 (4/CU)
  k_gout<<<1024, 256, 0, stream>>>(Fb, WTout, out_b, (float*)d_out, 1024);
}

// Round 21
// 153.429 us; speedup vs baseline: 1.0590x; 1.0590x over previous
//
#include <hip/hip_runtime.h>

#define BT 4096      // B*T
#define Dd 1024
#define Tt 2048
#define ATT_SCALE 0.18033688f  // 0.125 * log2(e)

typedef __attribute__((ext_vector_type(8))) short bf16x8;
typedef __attribute__((ext_vector_type(4))) float f32x4;
typedef __attribute__((ext_vector_type(4))) unsigned u32x4;

__device__ __forceinline__ short f2bf(float f) {
  unsigned u = __builtin_bit_cast(unsigned, f);
  u = (u + 0x7FFFu + ((u >> 16) & 1u)) >> 16;
  return (short)u;
}
__device__ __forceinline__ float bf2f(short s) {
  unsigned u = ((unsigned)(unsigned short)s) << 16;
  return __builtin_bit_cast(float, u);
}
__device__ __forceinline__ unsigned cvt_pk_bf16(float a, float b) {
  unsigned r;
  asm("v_cvt_pk_bf16_f32 %0, %1, %2" : "=v"(r) : "v"(a), "v"(b));
  return r;
}

__device__ __forceinline__ void load_lds16(const void* gsrc, void* ldst) {
  __builtin_amdgcn_global_load_lds(
      (const __attribute__((address_space(1))) void*)gsrc,
      (__attribute__((address_space(3))) void*)ldst, 16, 0, 0);
}

// --- merged prep: weight transposes (sections 0..1359) + x fp32->bf16 (1360..5455) --
__global__ __launch_bounds__(256) void k_wtall(
    const float* __restrict__ qkv_w, const float* __restrict__ memv_w,
    const float* __restrict__ out_w, const float* __restrict__ w1w,
    const float* __restrict__ w2w, const float* __restrict__ w1r,
    const float* __restrict__ w2r, const float* __restrict__ memg_w,
    short* __restrict__ WTall, short* __restrict__ WTout,
    const float* __restrict__ x, short* __restrict__ xb) {
  __shared__ float tile[64][65];
  const int bid = blockIdx.x;
  if (bid >= 1360) {  // cvt section: 4096 blocks x 256 float4
    int i = (bid - 1360) * 256 + threadIdx.x;
    float4 v = ((const float4*)x)[i];
    short4 o;
    o.x = f2bf(v.x); o.y = f2bf(v.y); o.z = f2bf(v.z); o.w = f2bf(v.w);
    ((short4*)xb)[i] = o;
    return;
  }
  const float* src;
  short* dst;
  int N, n0, k0, rowoff;
  if (bid < 768) {
    src = qkv_w; dst = WTall; N = 3072;
    n0 = (bid % 48) * 64; k0 = (bid / 48) * 64; rowoff = 0;
  } else if (bid < 1024) {
    int r = bid - 768;
    src = memv_w; dst = WTall; N = 1024;
    n0 = (r % 16) * 64; k0 = (r / 16) * 64; rowoff = 3072;
  } else if (bid < 1280) {
    int r = bid - 1024;
    src = out_w; dst = WTout; N = 1024;
    n0 = (r % 16) * 64; k0 = (r / 16) * 64; rowoff = 0;
  } else {
    int r = bid - 1280;
    int z = r / 16;
    src = z == 0 ? w1w : z == 1 ? w2w : z == 2 ? w1r : z == 3 ? w2r : memg_w;
    dst = WTall; N = (z == 4) ? 16 : 64;
    n0 = 0; k0 = (r % 16) * 64; rowoff = 4096 + z * 64;
  }
  const int c = threadIdx.x & 63, r4 = threadIdx.x >> 6;
#pragma unroll
  for (int i = 0; i < 16; ++i) {
    int r = i * 4 + r4;
    float v = 0.f;
    if (n0 + c < N) v = src[(size_t)(k0 + r) * N + n0 + c];
    tile[r][c] = v;
  }
  __syncthreads();
#pragma unroll
  for (int i = 0; i < 16; ++i) {
    int n = i * 4 + r4;
    if (n0 + n < N)
      dst[(size_t)(rowoff + n0 + n) * 1024 + k0 + c] = f2bf(tile[c][n]);
  }
}

// ====== 128x128 GEMM, BK=32 dbuf (32KB -> 4 blocks/CU), counted-vmcnt schedule =====
// q-range outputs are pre-scaled by ATT_SCALE (folds attention's softmax scale).
__global__ __launch_bounds__(256, 4) void k_g128(
    const short* __restrict__ A, const short* __restrict__ Bt,
    const float* __restrict__ bias, const float* __restrict__ bias2,
    short* __restrict__ oq, short* __restrict__ ok_, short* __restrict__ ov,
    short* __restrict__ omv, float* __restrict__ ocs, int K) {
  __shared__ __align__(16) short lds[16384];  // 32 KiB
  const int tid = threadIdx.x;
  const int wid = tid >> 6, lane = tid & 63;
  const int wr = wid >> 1, wc = wid & 1;
  const int ql = lane & 15, g = lane >> 4;
  int wg = blockIdx.x, xcd = wg & 7, idx = wg >> 3;
  const int n_t = idx >> 2;
  const int m_t = xcd * 4 + (idx & 3);
  const int nkt = K >> 5;
  const int bm = m_t * 128, bn = n_t * 128;
  f32x4 acc[4][4] = {};

  const short* srcA[2];
  const short* srcB[2];
  short* dstA[2];
  short* dstB[2];
#pragma unroll
  for (int j = 0; j < 2; ++j) {
    int o16 = j * 256 + tid;
    int rr = o16 >> 2, u = o16 & 3;
    int sp = u ^ ((rr >> 1) & 3);
    srcA[j] = A + (size_t)(bm + rr) * K + sp * 8;
    srcB[j] = Bt + (size_t)(bn + rr) * K + sp * 8;
    dstA[j] = lds + o16 * 8;
    dstB[j] = lds + 8192 + o16 * 8;
  }
#define STG(D, KT)                                                            \
  do {                                                                        \
    const int k0s = (KT) << 5;                                                \
    _Pragma("unroll") for (int j = 0; j < 2; ++j) {                           \
      load_lds16(srcA[j] + k0s, dstA[j] + (D)*4096);                          \
      load_lds16(srcB[j] + k0s, dstB[j] + (D)*4096);                          \
    }                                                                         \
  } while (0)

  const int sw = (g ^ ((ql >> 1) & 3)) << 4;
  const char* bA = (const char*)lds + wr * 4096 + ql * 64 + sw;
  const char* bB = (const char*)lds + 16384 + wc * 4096 + ql * 64 + sw;

#define RD_A(DST, DOFF, MQ)                                                    \
  _Pragma("unroll") for (int mi = 0; mi < 2; ++mi)                             \
      DST[mi] = *(const bf16x8*)(bA + (DOFF) + (MQ)*2048 + mi * 1024);
#define RD_B(DST, DOFF, NQ)                                                    \
  _Pragma("unroll") for (int ni = 0; ni < 2; ++ni)                             \
      DST[ni] = *(const bf16x8*)(bB + (DOFF) + (NQ)*2048 + ni * 1024);
#define MFMA4(AF, BF, MQ, NQ)                                                  \
  _Pragma("unroll") for (int mi = 0; mi < 2; ++mi)                             \
      _Pragma("unroll") for (int ni = 0; ni < 2; ++ni)                         \
          acc[(MQ)*2 + mi][(NQ)*2 + ni] =                                      \
      __builtin_amdgcn_mfma_f32_16x16x32_bf16(                                 \
          BF[ni], AF[mi], acc[(MQ)*2 + mi][(NQ)*2 + ni], 0, 0, 0)

  STG(0, 0);

  for (int kt = 0; kt < nkt; ++kt) {
    const int d = kt & 1;
    const int dOff = d << 13;
    const bool s1 = kt + 1 < nkt;
    if (s1) {
      STG(d ^ 1, kt + 1);
      asm volatile("s_waitcnt vmcnt(4)" ::: "memory");
    } else {
      asm volatile("s_waitcnt vmcnt(0)" ::: "memory");
    }
    __builtin_amdgcn_sched_barrier(0);
    __builtin_amdgcn_s_barrier();
    bf16x8 a0[2], a1[2], b0[2], b1[2];
    RD_A(a0, dOff, 0);
    RD_A(a1, dOff, 1);
    RD_B(b0, dOff, 0);
    RD_B(b1, dOff, 1);
    asm volatile("s_waitcnt lgkmcnt(0)" ::: "memory");
    __builtin_amdgcn_sched_barrier(0);
    __builtin_amdgcn_s_setprio(1);
    MFMA4(a0, b0, 0, 0);
    MFMA4(a0, b1, 0, 1);
    MFMA4(a1, b1, 1, 1);
    MFMA4(a1, b0, 1, 0);
    __builtin_amdgcn_s_setprio(0);
    __builtin_amdgcn_sched_barrier(0);
    __builtin_amdgcn_s_barrier();
    __builtin_amdgcn_sched_barrier(0);
  }
#undef MFMA4
#undef RD_A
#undef RD_B
#undef STG

#pragma unroll
  for (int a = 0; a < 4; ++a) {
    const int m = bm + wr * 64 + a * 16 + ql;
    const int b = m >> 11, t = m & 2047;
#pragma unroll
    for (int c = 0; c < 4; ++c) {
      const int n0 = bn + wc * 64 + c * 16 + g * 4;
      f32x4 v = acc[a][c];
      if (n0 < 3072) {
        const float4 b4 = *(const float4*)&bias[n0];
        v[0] += b4.x; v[1] += b4.y; v[2] += b4.z; v[3] += b4.w;
        const int sel = n0 >> 10, rem = n0 & 1023;
        if (sel == 0) {
          v[0] *= ATT_SCALE; v[1] *= ATT_SCALE; v[2] *= ATT_SCALE; v[3] *= ATT_SCALE;
          uint2 pk = make_uint2(cvt_pk_bf16(v[0], v[1]), cvt_pk_bf16(v[2], v[3]));
          *(uint2*)&oq[((size_t)(b * 16 + (rem >> 6)) * 2048 + t) * 64 + (rem & 63)] = pk;
        } else if (sel == 1) {
          uint2 pk = make_uint2(cvt_pk_bf16(v[0], v[1]), cvt_pk_bf16(v[2], v[3]));
          *(uint2*)&ok_[((size_t)(b * 16 + (rem >> 6)) * 2048 + t) * 64 + (rem & 63)] = pk;
        } else {
          uint2 pk = make_uint2(cvt_pk_bf16(v[0], v[1]), cvt_pk_bf16(v[2], v[3]));
          *(uint2*)&ov[(size_t)(b * 2048 + t) * 1024 + rem] = pk;
        }
      } else if (n0 < 4096) {
        const float4 b4 = *(const float4*)&bias2[n0 - 3072];
        v[0] += b4.x; v[1] += b4.y; v[2] += b4.z; v[3] += b4.w;
        uint2 pk = make_uint2(cvt_pk_bf16(v[0], v[1]), cvt_pk_bf16(v[2], v[3]));
        *(uint2*)&omv[(size_t)(b * 2048 + t) * 1024 + n0 - 3072] = pk;
      } else if (n0 < 4368) {
        *(f32x4*)&ocs[(size_t)(b * 2048 + t) * 272 + n0 - 4096] = v;
      }
    }
  }
}

// ====== out-GEMM: 64x64, BK=32 dbuf (16KB), counted vmcnt(2), grid 1024 (4/CU) =====
__global__ __launch_bounds__(256, 4) void k_gout(
    const short* __restrict__ A, const short* __restrict__ Bt,
    const float* __restrict__ bias, float* __restrict__ C, int K) {
  __shared__ __align__(16) short lds[8192];  // 16 KiB
  const int tid = threadIdx.x;
  const int wid = tid >> 6, lane = tid & 63;
  const int wr = wid >> 1, wc = wid & 1;
  const int ql = lane & 15, g = lane >> 4;
  int wg = blockIdx.x, xcd = wg & 7, idx = wg >> 3;
  const int n_t = idx >> 3, m_t = xcd * 8 + (idx & 7);
  const int bm = m_t * 64, bn = n_t * 64;
  const int nkt = K >> 5;
  f32x4 acc[2][2] = {};

  const short* srcA;
  const short* srcB;
  short* dstA;
  short* dstB;
  {
    int rr = tid >> 2, u = tid & 3;
    int sp = u ^ ((rr >> 1) & 3);
    srcA = A + (size_t)(bm + rr) * K + sp * 8;
    srcB = Bt + (size_t)(bn + rr) * K + sp * 8;
    dstA = lds + tid * 8;
    dstB = lds + 4096 + tid * 8;
  }
#define STG(D, KT)                                                            \
  do {                                                                        \
    const int k0s = (KT) << 5;                                                \
    load_lds16(srcA + k0s, dstA + (D)*2048);                                  \
    load_lds16(srcB + k0s, dstB + (D)*2048);                                  \
  } while (0)

  const int sw = (g ^ ((ql >> 1) & 3)) << 4;
  const char* bA = (const char*)lds + wr * 2048 + ql * 64 + sw;
  const char* bB = (const char*)lds + 8192 + wc * 2048 + ql * 64 + sw;

  STG(0, 0);

  for (int kt = 0; kt < nkt; ++kt) {
    const int d = kt & 1;
    const int dOff = d << 12;
    const bool s1 = kt + 1 < nkt;
    if (s1) {
      STG(d ^ 1, kt + 1);
      asm volatile("s_waitcnt vmcnt(2)" ::: "memory");
    } else {
      asm volatile("s_waitcnt vmcnt(0)" ::: "memory");
    }
    __builtin_amdgcn_sched_barrier(0);
    __builtin_amdgcn_s_barrier();
    bf16x8 af[2], bf2[2];
#pragma unroll
    for (int mi = 0; mi < 2; ++mi)
      af[mi] = *(const bf16x8*)(bA + dOff + mi * 1024);
#pragma unroll
    for (int ni = 0; ni < 2; ++ni)
      bf2[ni] = *(const bf16x8*)(bB + dOff + ni * 1024);
    asm volatile("s_waitcnt lgkmcnt(0)" ::: "memory");
    __builtin_amdgcn_sched_barrier(0);
    __builtin_amdgcn_s_setprio(1);
#pragma unroll
    for (int mi = 0; mi < 2; ++mi)
#pragma unroll
      for (int ni = 0; ni < 2; ++ni)
        acc[mi][ni] = __builtin_amdgcn_mfma_f32_16x16x32_bf16(
            bf2[ni], af[mi], acc[mi][ni], 0, 0, 0);
    __builtin_amdgcn_s_setprio(0);
    __builtin_amdgcn_sched_barrier(0);
    __builtin_amdgcn_s_barrier();
    __builtin_amdgcn_sched_barrier(0);
  }
#undef STG

#pragma unroll
  for (int a = 0; a < 2; ++a) {
    const int m = bm + wr * 32 + a * 16 + ql;
#pragma unroll
    for (int c = 0; c < 2; ++c) {
      const int n0 = bn + wc * 32 + c * 16 + g * 4;
      f32x4 v = acc[a][c];
      const float4 b4 = *(const float4*)&bias[n0];
      v[0] += b4.x; v[1] += b4.y; v[2] += b4.z; v[3] += b4.w;
      *(f32x4*)&C[(size_t)m * 1024 + n0] = v;
    }
  }
}

// -------- merged: Plücker lines (bid<256) || V transpose (bid>=256) -----------------
__global__ __launch_bounds__(256) void k_lv(const float* __restrict__ Cs,
                                            const float* __restrict__ Jm,
                                            float* __restrict__ u,
                                            float* __restrict__ rr,
                                            const short* __restrict__ vtmp,
                                            short* __restrict__ vb) {
  __shared__ short tile[64][68];
  const int bid = blockIdx.x;
  if (bid >= 256) {  // vtrans section: 1024 blocks
    const int r2 = bid - 256;
    const int bh = r2 >> 5, b = bh >> 4, h = bh & 15;
    const int t0 = (r2 & 31) * 64;
    const int tid = threadIdx.x;
#pragma unroll
    for (int pass = 0; pass < 16; ++pass) {
      int r = pass * 4 + (tid >> 6);
      int c = tid & 63;
      tile[r][c] = vtmp[((size_t)(b * 2048) + t0 + r) * 1024 + h * 64 + c];
    }
    __syncthreads();
#pragma unroll
    for (int pass = 0; pass < 16; ++pass) {
      int r = pass * 4 + (tid >> 6);
      int c = tid & 63;
      int cp = (c & 32) | (((c >> 2) & 3) << 3) | (((c >> 4) & 1) << 2) | (c & 3);
      vb[(((size_t)b * 16 + h) * 64 + r) * 2048 + t0 + cp] = tile[c][r];
    }
    return;
  }
  int idx = bid * 256 + threadIdx.x;  // [0, 65536)
  int h = idx & 15, t = (idx >> 4) & 2047, b = idx >> 15;
  const float* rowx = Cs + (size_t)(b * 2048 + t) * 272;
  float w1[4], w2[4], r1[4], r2v[4];
  if (t == 0) {
#pragma unroll
    for (int i = 0; i < 4; ++i) w1[i] = 0.f;
  } else {
    const float* prev = Cs + (size_t)(b * 2048 + t - 1) * 272;
#pragma unroll
    for (int i = 0; i < 4; ++i) w1[i] = prev[h * 4 + i];
  }
#pragma unroll
  for (int i = 0; i < 4; ++i) {
    w2[i] = rowx[64 + h * 4 + i];
    r1[i] = rowx[128 + h * 4 + i];
    r2v[i] = rowx[192 + h * 4 + i];
  }
  const int pi[6] = {0, 0, 0, 1, 1, 2}, pj[6] = {1, 2, 3, 2, 3, 3};
  float wl[6], rl[6], nw = 0.f, nr = 0.f;
#pragma unroll
  for (int e = 0; e < 6; ++e) {
    wl[e] = w1[pi[e]] * w2[pj[e]] - w1[pj[e]] * w2[pi[e]];
    rl[e] = r1[pi[e]] * r2v[pj[e]] - r1[pj[e]] * r2v[pi[e]];
    nw += wl[e] * wl[e];
    nr += rl[e] * rl[e];
  }
  nw = 1.f / fmaxf(sqrtf(nw), 1e-12f);
  nr = 1.f / fmaxf(sqrtf(nr), 1e-12f);
  size_t base = (((size_t)b * 16 + h) * 2048 + t) * 6;
#pragma unroll
  for (int jc = 0; jc < 6; ++jc) {
    float s = 0.f;
#pragma unroll
    for (int i = 0; i < 6; ++i) s += wl[i] * Jm[i * 6 + jc];
    u[base + jc] = s * nw;
    rr[base + jc] = rl[jc] * nr;
  }
}

// ---------------- causal flash attention, swapped-operand, UNPAIRED ----------------
// q pre-scaled in GEMM epilogue; exact defer-rescale via __any.
__device__ __forceinline__ void attn_core(const bf16x8 qa[2], f32x4 o[4],
                                          float& m, float& l,
                                          const short* __restrict__ Kc,
                                          const short* __restrict__ Vc,
                                          int qt, int kt, int qglob,
                                          int ql, int g) {
  const int kv0 = kt * 64;
  f32x4 s4[4];
  __builtin_amdgcn_s_setprio(1);
#pragma unroll
  for (int nt = 0; nt < 4; ++nt) {
    int krow = nt * 16 + ql;
    f32x4 s = {0.f, 0.f, 0.f, 0.f};
#pragma unroll
    for (int kc = 0; kc < 2; ++kc) {
      int sl = (kc * 4 + g) ^ (krow & 7);
      bf16x8 af = *(const bf16x8*)&Kc[krow * 64 + sl * 8];
      s = __builtin_amdgcn_mfma_f32_16x16x32_bf16(af, qa[kc], s, 0, 0, 0);
    }
    s4[nt] = s;
  }
  __builtin_amdgcn_s_setprio(0);
  float mt = -1e30f;
  const bool diag = (kt == qt);
#pragma unroll
  for (int nt = 0; nt < 4; ++nt)
#pragma unroll
    for (int rg = 0; rg < 4; ++rg) {
      float v = s4[nt][rg];
      if (diag) {
        int kk = kv0 + nt * 16 + g * 4 + rg;
        v = (kk <= qglob) ? v : -1e30f;
      }
      s4[nt][rg] = v;
      mt = fmaxf(mt, v);
    }
  mt = fmaxf(mt, __shfl_xor(mt, 16, 64));
  mt = fmaxf(mt, __shfl_xor(mt, 32, 64));
  float mnew = fmaxf(m, mt);
  if (__any(mnew > m)) {  // exact: skip only when sf==1 for all lanes
    float sf = __builtin_amdgcn_exp2f(m - mnew);
    m = mnew;
    l *= sf;
#pragma unroll
    for (int nt = 0; nt < 4; ++nt) o[nt] *= sf;
  }
  float rs = 0.f;
#pragma unroll
  for (int nt = 0; nt < 4; ++nt)
#pragma unroll
    for (int rg = 0; rg < 4; ++rg) {
      float p = __builtin_amdgcn_exp2f(s4[nt][rg] - m);
      s4[nt][rg] = p;
      rs += p;
    }
  rs += __shfl_xor(rs, 16, 64);
  rs += __shfl_xor(rs, 32, 64);
  l += rs;
  bf16x8 pf[2];
#pragma unroll
  for (int kc = 0; kc < 2; ++kc) {
    u32x4 w;
    w[0] = cvt_pk_bf16(s4[2 * kc][0], s4[2 * kc][1]);
    w[1] = cvt_pk_bf16(s4[2 * kc][2], s4[2 * kc][3]);
    w[2] = cvt_pk_bf16(s4[2 * kc + 1][0], s4[2 * kc + 1][1]);
    w[3] = cvt_pk_bf16(s4[2 * kc + 1][2], s4[2 * kc + 1][3]);
    pf[kc] = __builtin_bit_cast(bf16x8, w);
  }
  __builtin_amdgcn_s_setprio(1);
#pragma unroll
  for (int nt2 = 0; nt2 < 4; ++nt2) {
    int d = nt2 * 16 + ql;
#pragma unroll
    for (int kc = 0; kc < 2; ++kc) {
      int sl = (kc * 4 + g) ^ (d & 7);
      bf16x8 vf = *(const bf16x8*)&Vc[d * 64 + sl * 8];
      o[nt2] = __builtin_amdgcn_mfma_f32_16x16x32_bf16(vf, pf[kc], o[nt2], 0, 0, 0);
    }
  }
  __builtin_amdgcn_s_setprio(0);
}

// epilogue with fused gmean*memval: Fb = bf16(o/l + gm*mvb)
__device__ __forceinline__ void attn_epi(const f32x4 o[4], float l,
                                         short* __restrict__ Fb,
                                         const short* __restrict__ mvb,
                                         const float* __restrict__ gm,
                                         float* ep,
                                         int b, int h, int qt, int wave, int lane) {
  const int ql = lane & 15, g = lane >> 4;
  float inv = 1.f / l;
#pragma unroll
  for (int nt2 = 0; nt2 < 4; ++nt2) {
    f32x4 v = o[nt2] * inv;
    *(f32x4*)&ep[ql * 64 + (((nt2 * 4 + g) ^ (ql & 7)) << 2)] = v;
  }
  const size_t rowbase = ((size_t)b * 2048 + qt * 64 + wave * 16);
  short* srow = Fb + rowbase * 1024 + h * 64;
  const short* mrow = mvb + rowbase * 1024 + h * 64;
  const float* grow = gm + rowbase;
#pragma unroll
  for (int p = 0; p < 8; ++p) {
    int prow = p * 2 + (lane >> 5);
    int d2 = (lane & 31) * 2;
    const float* rp = &ep[prow * 64 + (((d2 >> 2) ^ (prow & 7)) << 2) + (d2 & 3)];
    float2 vv = *(const float2*)rp;
    float gg = grow[prow];
    unsigned mvp = *(const unsigned*)&mrow[(size_t)prow * 1024 + d2];
    float m0 = bf2f((short)(mvp & 0xffff));
    float m1 = bf2f((short)(mvp >> 16));
    *(unsigned*)&srow[(size_t)prow * 1024 + d2] =
        cvt_pk_bf16(vv.x + gg * m0, vv.y + gg * m1);
  }
}

__global__ __launch_bounds__(256, 4) void k_attn(const short* __restrict__ Q,
                                                 const short* __restrict__ Kg,
                                                 const short* __restrict__ Vg,
                                                 const short* __restrict__ mvb,
                                                 const float* __restrict__ gm,
                                                 short* __restrict__ Fb) {
  __shared__ short Kt[2][64 * 64];  // 16KB
  __shared__ short Vt[2][64 * 64];  // 16KB
  const int wg = blockIdx.x;                 // 1024 blocks
  const int x = wg & 7, r = wg >> 3;         // XCD x owns bh in {4x..4x+3}
  const int q = r >> 2, j = r & 3;           // quad-balanced (bh, qt)
  const int bh = 4 * x + j;
  const int q2 = (q + 16) & 31;
  const int qt = (j == 0) ? q : (j == 1) ? 31 - q : (j == 2) ? q2 : 31 - q2;
  const int b = bh >> 4, h = bh & 15;
  const int tid = threadIdx.x;
  const int wave = tid >> 6, lane = tid & 63;
  const int ql = lane & 15, g = lane >> 4;
  const int qglob = qt * 64 + wave * 16 + ql;
  const short* qr = Q + ((size_t)bh * 2048 + qglob) * 64;
  bf16x8 qa[2];
  qa[0] = *(const bf16x8*)&qr[g * 8];
  qa[1] = *(const bf16x8*)&qr[32 + g * 8];
  f32x4 o[4] = {};
  float m = -1e30f, l = 0.f;
  const short* kgb = Kg + (size_t)bh * 2048 * 64;
  const short* vgb = Vg + (size_t)bh * 64 * 2048;

  auto stage = [&](int buf, int kt) {
    int kv0 = kt * 64;
#pragma unroll
    for (int jj = 0; jj < 2; ++jj) {
      int slot = (wave * 2 + jj) * 64 + lane;
      int rr = slot >> 3, s8 = slot & 7;
      int ss = s8 ^ (rr & 7);
      load_lds16(kgb + (size_t)(kv0 + rr) * 64 + ss * 8, &Kt[buf][slot * 8]);
      load_lds16(vgb + (size_t)rr * 2048 + kv0 + ss * 8, &Vt[buf][slot * 8]);
    }
  };

  stage(0, 0);
  int cur = 0;
  for (int it = 0; it <= qt; ++it) {
    __syncthreads();
    if (it < qt) stage(cur ^ 1, it + 1);
    attn_core(qa, o, m, l, Kt[cur], Vt[cur], qt, it, qglob, ql, g);
    cur ^= 1;
  }
  __syncthreads();
  float* ep = (float*)&Kt[0][0] + wave * 1024;  // 16KB scratch across Kt
  attn_epi(o, l, Fb, mvb, gm, ep, b, h, qt, wave, lane);
}

// ------------- decayed prefix scan per channel: w[bh][ch][t] = S_t[p][q] -------------
__global__ __launch_bounds__(256) void k_scanw(const float* __restrict__ u,
                                               float* __restrict__ w,
                                               const float* __restrict__ decays) {
  __shared__ float wtot[4];
  const int ch = blockIdx.x;
  const int bh = blockIdx.y;
  const float d = decays[bh & 15];
  const int p = ch / 6, q = ch % 6;
  const int tid = threadIdx.x, lane = tid & 63, wv = tid >> 6;
  const float* ub = u + (size_t)bh * 2048 * 6;
  const int t0 = tid * 8;
  float z[8];
  float a = 0.f;
#pragma unroll
  for (int i = 0; i < 8; ++i) {
    float up = ub[(t0 + i) * 6 + p], uq = ub[(t0 + i) * 6 + q];
    z[i] = up * uq;
    a = d * (a + z[i]);
  }
  float d8 = d * d; d8 *= d8; d8 *= d8;
  float I = a;
  float ds = d8;
#pragma unroll
  for (int s = 1; s < 64; s <<= 1) {
    float v = __shfl_up(I, s, 64);
    if (lane >= s) I += ds * v;
    ds *= ds;
  }
  if (lane == 63) wtot[wv] = I;
  __syncthreads();
  float carry = 0.f;
  for (int w2 = 0; w2 < wv; ++w2) carry = carry * ds + wtot[w2];
  float dlp1 = exp2f(log2f(d8) * (float)(lane + 1));
  float Ig = I + dlp1 * carry;
  float E = __shfl_up(Ig, 1, 64);
  if (lane == 0) E = carry;
  float S = E;
  float out[8];
#pragma unroll
  for (int i = 0; i < 8; ++i) {
    out[i] = S;
    S = d * (S + z[i]);
  }
  float4* wp = (float4*)(w + ((size_t)bh * 36 + ch) * 2048 + t0);
  wp[0] = make_float4(out[0], out[1], out[2], out[3]);
  wp[1] = make_float4(out[4], out[5], out[6], out[7]);
}

// ------------- scores[bh][t] = sum_ch r[p]*r[q] * w[bh][ch][t] ----------------------
__global__ __launch_bounds__(256) void k_scandot(const float* __restrict__ rr,
                                                 const float* __restrict__ w,
                                                 float* __restrict__ scores) {
  const int bh = blockIdx.y;
  const int t = blockIdx.x * 256 + threadIdx.x;
  const float* rb = rr + ((size_t)bh * 2048 + t) * 6;
  float r[6];
#pragma unroll
  for (int i = 0; i < 6; ++i) r[i] = rb[i];
  const float* wb = w + (size_t)bh * 36 * 2048 + t;
  float acc = 0.f;
#pragma unroll
  for (int ch = 0; ch < 36; ++ch)
    acc += r[ch / 6] * r[ch % 6] * wb[(size_t)ch * 2048];
  scores[(size_t)bh * 2048 + t] = acc;
}

// ---------------- gate: gmean[b,t] = mean_h sig(score*scale_h)*sig(memg) -----------
__global__ __launch_bounds__(256) void k_gate(const float* __restrict__ scores,
                                              const float* __restrict__ Cs,
                                              const float* __restrict__ memg_b,
                                              const float* __restrict__ mem_scale,
                                              float* __restrict__ gmean) {
  int idx = blockIdx.x * 256 + threadIdx.x;
  if (idx >= BT) return;
  int b = idx >> 11, t = idx & 2047;
  float acc = 0.f;
#pragma unroll
  for (int h = 0; h < 16; ++h) {
    float s = scores[((size_t)(b * 16 + h) * 2048) + t];
    float gl = Cs[(size_t)idx * 272 + 256 + h] + memg_b[h];
    float a = 1.f / (1.f + __expf(-s * mem_scale[h]));
    float gg = 1.f / (1.f + __expf(-gl));
    acc += a * gg;
  }
  gmean[idx] = acc * (1.f / 16.f);
}

extern "C" void kernel_launch(void* const* d_in, const int* in_sizes, int n_in,
                              void* d_out, int out_size, void* d_ws, size_t ws_size,
                              hipStream_t stream) {
  const float* x = (const float*)d_in[0];
  const float* qkv_w = (const float*)d_in[1];
  const float* qkv_b = (const float*)d_in[2];
  const float* w1w = (const float*)d_in[3];
  const float* w2w = (const float*)d_in[4];
  const float* w1r = (const float*)d_in[5];
  const float* w2r = (const float*)d_in[6];
  const float* memv_w = (const float*)d_in[7];
  const float* memv_b = (const float*)d_in[8];
  const float* memg_w = (const float*)d_in[9];
  const float* memg_b = (const float*)d_in[10];
  const float* mem_scale = (const float*)d_in[11];
  const float* out_w = (const float*)d_in[12];
  const float* out_b = (const float*)d_in[13];
  const float* Jm = (const float*)d_in[14];
  const float* decays = (const float*)d_in[15];

  char* w = (char*)d_ws;
  size_t off = 0;
  auto alloc = [&](size_t bytes) -> void* {
    void* p = w + off;
    off += (bytes + 255) & ~(size_t)255;
    return p;
  };
  short* xb = (short*)alloc((size_t)BT * Dd * 2);
  short* WTall = (short*)alloc((size_t)4480 * 1024 * 2);  // qkv|memv|sm
  short* WTout = (short*)alloc((size_t)1024 * 1024 * 2);
  short* qb = (short*)alloc((size_t)32 * 2048 * 64 * 2);
  short* kb = (short*)alloc((size_t)32 * 2048 * 64 * 2);
  short* vtmp = (short*)alloc((size_t)BT * 1024 * 2);
  short* vb = (short*)alloc((size_t)32 * 64 * 2048 * 2);
  float* Csm = (float*)alloc((size_t)BT * 272 * 4);
  float* ua = (float*)alloc((size_t)32 * 2048 * 6 * 4);
  float* ra = (float*)alloc((size_t)32 * 2048 * 6 * 4);
  float* sc = (float*)alloc((size_t)32 * 2048 * 4);
  float* gm = (float*)alloc((size_t)BT * 4);
  short* mvb = (short*)alloc((size_t)BT * 1024 * 2);
  short* Fb = (short*)alloc((size_t)BT * Dd * 2);
  float* wscan = (float*)alloc((size_t)32 * 36 * 2048 * 4);
  (void)ws_size; (void)in_sizes; (void)n_in; (void)out_size;

  // prep: all weight transposes + x->bf16 in ONE launch
  k_wtall<<<5456, 256, 0, stream>>>(qkv_w, memv_w, out_w, w1w, w2w, w1r, w2r,
                                    memg_w, WTall, WTout, x, xb);

  // fused GEMM: qkv (q pre-scaled) | memv->bf16 | sm->Csm over N=4480, 4 blocks/CU
  k_g128<<<1120, 256, 0, stream>>>(xb, WTall, qkv_b, memv_b,
                                   qb, kb, vtmp, mvb, Csm, 1024);

  // lines (256 blocks) || vtrans (1024 blocks) in one launch
  k_lv<<<1280, 256, 0, stream>>>(Csm, Jm, ua, ra, vtmp, vb);

  // decay scan + scandot + gate (well-parallelized, as r18)
  k_scanw<<<dim3(36, 32), 256, 0, stream>>>(ua, wscan, decays);
  k_scandot<<<dim3(8, 32), 256, 0, stream>>>(ra, wscan, sc);
  k_gate<<<(BT + 255) / 256, 256, 0, stream>>>(sc, Csm, memg_b, mem_scale, gm);

  // attention (epilogue fuses + gm*mvb -> Fb): 1024 blocks, 4/CU, quad-balanced
  k_attn<<<1024, 256, 0, stream>>>(qb, kb, vb, mvb, gm, Fb);

  // final GEMM: 64x64-tile full-K, fp32 + bias -> d_out, grid 1024 (4/CU)
  k_gout<<<1024, 256, 0, stream>>>(Fb, WTout, out_b, (float*)d_out, 1024);
}

// Round 22
// 152.656 us; speedup vs baseline: 1.0644x; 1.0051x over previous
//
#include <hip/hip_runtime.h>

#define BT 4096      // B*T
#define Dd 1024
#define Tt 2048
#define ATT_SCALE 0.18033688f  // 0.125 * log2(e)

typedef __attribute__((ext_vector_type(8))) short bf16x8;
typedef __attribute__((ext_vector_type(4))) float f32x4;
typedef __attribute__((ext_vector_type(4))) unsigned u32x4;

__device__ __forceinline__ short f2bf(float f) {
  unsigned u = __builtin_bit_cast(unsigned, f);
  u = (u + 0x7FFFu + ((u >> 16) & 1u)) >> 16;
  return (short)u;
}
__device__ __forceinline__ float bf2f(short s) {
  unsigned u = ((unsigned)(unsigned short)s) << 16;
  return __builtin_bit_cast(float, u);
}
__device__ __forceinline__ unsigned cvt_pk_bf16(float a, float b) {
  unsigned r;
  asm("v_cvt_pk_bf16_f32 %0, %1, %2" : "=v"(r) : "v"(a), "v"(b));
  return r;
}

__device__ __forceinline__ void load_lds16(const void* gsrc, void* ldst) {
  __builtin_amdgcn_global_load_lds(
      (const __attribute__((address_space(1))) void*)gsrc,
      (__attribute__((address_space(3))) void*)ldst, 16, 0, 0);
}

// --- merged prep: weight transposes (sections 0..1359) + x fp32->bf16 (1360..5455) --
__global__ __launch_bounds__(256) void k_wtall(
    const float* __restrict__ qkv_w, const float* __restrict__ memv_w,
    const float* __restrict__ out_w, const float* __restrict__ w1w,
    const float* __restrict__ w2w, const float* __restrict__ w1r,
    const float* __restrict__ w2r, const float* __restrict__ memg_w,
    short* __restrict__ WTall, short* __restrict__ WTout,
    const float* __restrict__ x, short* __restrict__ xb) {
  __shared__ float tile[64][65];
  const int bid = blockIdx.x;
  if (bid >= 1360) {  // cvt section: 4096 blocks x 256 float4
    int i = (bid - 1360) * 256 + threadIdx.x;
    float4 v = ((const float4*)x)[i];
    short4 o;
    o.x = f2bf(v.x); o.y = f2bf(v.y); o.z = f2bf(v.z); o.w = f2bf(v.w);
    ((short4*)xb)[i] = o;
    return;
  }
  const float* src;
  short* dst;
  int N, n0, k0, rowoff;
  if (bid < 768) {
    src = qkv_w; dst = WTall; N = 3072;
    n0 = (bid % 48) * 64; k0 = (bid / 48) * 64; rowoff = 0;
  } else if (bid < 1024) {
    int r = bid - 768;
    src = memv_w; dst = WTall; N = 1024;
    n0 = (r % 16) * 64; k0 = (r / 16) * 64; rowoff = 3072;
  } else if (bid < 1280) {
    int r = bid - 1024;
    src = out_w; dst = WTout; N = 1024;
    n0 = (r % 16) * 64; k0 = (r / 16) * 64; rowoff = 0;
  } else {
    int r = bid - 1280;
    int z = r / 16;
    src = z == 0 ? w1w : z == 1 ? w2w : z == 2 ? w1r : z == 3 ? w2r : memg_w;
    dst = WTall; N = (z == 4) ? 16 : 64;
    n0 = 0; k0 = (r % 16) * 64; rowoff = 4096 + z * 64;
  }
  const int c = threadIdx.x & 63, r4 = threadIdx.x >> 6;
#pragma unroll
  for (int i = 0; i < 16; ++i) {
    int r = i * 4 + r4;
    float v = 0.f;
    if (n0 + c < N) v = src[(size_t)(k0 + r) * N + n0 + c];
    tile[r][c] = v;
  }
  __syncthreads();
#pragma unroll
  for (int i = 0; i < 16; ++i) {
    int n = i * 4 + r4;
    if (n0 + n < N)
      dst[(size_t)(rowoff + n0 + n) * 1024 + k0 + c] = f2bf(tile[c][n]);
  }
}

// ====== 128x128 GEMM, BK=32 dbuf (32KB -> 4 blocks/CU), counted-vmcnt schedule =====
// q-range outputs are pre-scaled by ATT_SCALE (folds attention's softmax scale).
__global__ __launch_bounds__(256, 4) void k_g128(
    const short* __restrict__ A, const short* __restrict__ Bt,
    const float* __restrict__ bias, const float* __restrict__ bias2,
    short* __restrict__ oq, short* __restrict__ ok_, short* __restrict__ ov,
    short* __restrict__ omv, float* __restrict__ ocs, int K) {
  __shared__ __align__(16) short lds[16384];  // 32 KiB
  const int tid = threadIdx.x;
  const int wid = tid >> 6, lane = tid & 63;
  const int wr = wid >> 1, wc = wid & 1;
  const int ql = lane & 15, g = lane >> 4;
  int wg = blockIdx.x, xcd = wg & 7, idx = wg >> 3;
  const int n_t = idx >> 2;
  const int m_t = xcd * 4 + (idx & 3);
  const int nkt = K >> 5;
  const int bm = m_t * 128, bn = n_t * 128;
  f32x4 acc[4][4] = {};

  const short* srcA[2];
  const short* srcB[2];
  short* dstA[2];
  short* dstB[2];
#pragma unroll
  for (int j = 0; j < 2; ++j) {
    int o16 = j * 256 + tid;
    int rr = o16 >> 2, u = o16 & 3;
    int sp = u ^ ((rr >> 1) & 3);
    srcA[j] = A + (size_t)(bm + rr) * K + sp * 8;
    srcB[j] = Bt + (size_t)(bn + rr) * K + sp * 8;
    dstA[j] = lds + o16 * 8;
    dstB[j] = lds + 8192 + o16 * 8;
  }
#define STG(D, KT)                                                            \
  do {                                                                        \
    const int k0s = (KT) << 5;                                                \
    _Pragma("unroll") for (int j = 0; j < 2; ++j) {                           \
      load_lds16(srcA[j] + k0s, dstA[j] + (D)*4096);                          \
      load_lds16(srcB[j] + k0s, dstB[j] + (D)*4096);                          \
    }                                                                         \
  } while (0)

  const int sw = (g ^ ((ql >> 1) & 3)) << 4;
  const char* bA = (const char*)lds + wr * 4096 + ql * 64 + sw;
  const char* bB = (const char*)lds + 16384 + wc * 4096 + ql * 64 + sw;

#define RD_A(DST, DOFF, MQ)                                                    \
  _Pragma("unroll") for (int mi = 0; mi < 2; ++mi)                             \
      DST[mi] = *(const bf16x8*)(bA + (DOFF) + (MQ)*2048 + mi * 1024);
#define RD_B(DST, DOFF, NQ)                                                    \
  _Pragma("unroll") for (int ni = 0; ni < 2; ++ni)                             \
      DST[ni] = *(const bf16x8*)(bB + (DOFF) + (NQ)*2048 + ni * 1024);
#define MFMA4(AF, BF, MQ, NQ)                                                  \
  _Pragma("unroll") for (int mi = 0; mi < 2; ++mi)                             \
      _Pragma("unroll") for (int ni = 0; ni < 2; ++ni)                         \
          acc[(MQ)*2 + mi][(NQ)*2 + ni] =                                      \
      __builtin_amdgcn_mfma_f32_16x16x32_bf16(                                 \
          BF[ni], AF[mi], acc[(MQ)*2 + mi][(NQ)*2 + ni], 0, 0, 0)

  STG(0, 0);

  for (int kt = 0; kt < nkt; ++kt) {
    const int d = kt & 1;
    const int dOff = d << 13;
    const bool s1 = kt + 1 < nkt;
    if (s1) {
      STG(d ^ 1, kt + 1);
      asm volatile("s_waitcnt vmcnt(4)" ::: "memory");
    } else {
      asm volatile("s_waitcnt vmcnt(0)" ::: "memory");
    }
    __builtin_amdgcn_sched_barrier(0);
    __builtin_amdgcn_s_barrier();
    bf16x8 a0[2], a1[2], b0[2], b1[2];
    RD_A(a0, dOff, 0);
    RD_A(a1, dOff, 1);
    RD_B(b0, dOff, 0);
    RD_B(b1, dOff, 1);
    asm volatile("s_waitcnt lgkmcnt(0)" ::: "memory");
    __builtin_amdgcn_sched_barrier(0);
    __builtin_amdgcn_s_setprio(1);
    MFMA4(a0, b0, 0, 0);
    MFMA4(a0, b1, 0, 1);
    MFMA4(a1, b1, 1, 1);
    MFMA4(a1, b0, 1, 0);
    __builtin_amdgcn_s_setprio(0);
    __builtin_amdgcn_sched_barrier(0);
    __builtin_amdgcn_s_barrier();
    __builtin_amdgcn_sched_barrier(0);
  }
#undef MFMA4
#undef RD_A
#undef RD_B
#undef STG

#pragma unroll
  for (int a = 0; a < 4; ++a) {
    const int m = bm + wr * 64 + a * 16 + ql;
    const int b = m >> 11, t = m & 2047;
#pragma unroll
    for (int c = 0; c < 4; ++c) {
      const int n0 = bn + wc * 64 + c * 16 + g * 4;
      f32x4 v = acc[a][c];
      if (n0 < 3072) {
        const float4 b4 = *(const float4*)&bias[n0];
        v[0] += b4.x; v[1] += b4.y; v[2] += b4.z; v[3] += b4.w;
        const int sel = n0 >> 10, rem = n0 & 1023;
        if (sel == 0) {
          v[0] *= ATT_SCALE; v[1] *= ATT_SCALE; v[2] *= ATT_SCALE; v[3] *= ATT_SCALE;
          uint2 pk = make_uint2(cvt_pk_bf16(v[0], v[1]), cvt_pk_bf16(v[2], v[3]));
          *(uint2*)&oq[((size_t)(b * 16 + (rem >> 6)) * 2048 + t) * 64 + (rem & 63)] = pk;
        } else if (sel == 1) {
          uint2 pk = make_uint2(cvt_pk_bf16(v[0], v[1]), cvt_pk_bf16(v[2], v[3]));
          *(uint2*)&ok_[((size_t)(b * 16 + (rem >> 6)) * 2048 + t) * 64 + (rem & 63)] = pk;
        } else {
          uint2 pk = make_uint2(cvt_pk_bf16(v[0], v[1]), cvt_pk_bf16(v[2], v[3]));
          *(uint2*)&ov[(size_t)(b * 2048 + t) * 1024 + rem] = pk;
        }
      } else if (n0 < 4096) {
        const float4 b4 = *(const float4*)&bias2[n0 - 3072];
        v[0] += b4.x; v[1] += b4.y; v[2] += b4.z; v[3] += b4.w;
        uint2 pk = make_uint2(cvt_pk_bf16(v[0], v[1]), cvt_pk_bf16(v[2], v[3]));
        *(uint2*)&omv[(size_t)(b * 2048 + t) * 1024 + n0 - 3072] = pk;
      } else if (n0 < 4368) {
        *(f32x4*)&ocs[(size_t)(b * 2048 + t) * 272 + n0 - 4096] = v;
      }
    }
  }
}

// ====== out-GEMM: 64x64, BK=32 dbuf (16KB), counted vmcnt(2), grid 1024 (4/CU) =====
__global__ __launch_bounds__(256, 4) void k_gout(
    const short* __restrict__ A, const short* __restrict__ Bt,
    const float* __restrict__ bias, float* __restrict__ C, int K) {
  __shared__ __align__(16) short lds[8192];  // 16 KiB
  const int tid = threadIdx.x;
  const int wid = tid >> 6, lane = tid & 63;
  const int wr = wid >> 1, wc = wid & 1;
  const int ql = lane & 15, g = lane >> 4;
  int wg = blockIdx.x, xcd = wg & 7, idx = wg >> 3;
  const int n_t = idx >> 3, m_t = xcd * 8 + (idx & 7);
  const int bm = m_t * 64, bn = n_t * 64;
  const int nkt = K >> 5;
  f32x4 acc[2][2] = {};

  const short* srcA;
  const short* srcB;
  short* dstA;
  short* dstB;
  {
    int rr = tid >> 2, u = tid & 3;
    int sp = u ^ ((rr >> 1) & 3);
    srcA = A + (size_t)(bm + rr) * K + sp * 8;
    srcB = Bt + (size_t)(bn + rr) * K + sp * 8;
    dstA = lds + tid * 8;
    dstB = lds + 4096 + tid * 8;
  }
#define STG(D, KT)                                                            \
  do {                                                                        \
    const int k0s = (KT) << 5;                                                \
    load_lds16(srcA + k0s, dstA + (D)*2048);                                  \
    load_lds16(srcB + k0s, dstB + (D)*2048);                                  \
  } while (0)

  const int sw = (g ^ ((ql >> 1) & 3)) << 4;
  const char* bA = (const char*)lds + wr * 2048 + ql * 64 + sw;
  const char* bB = (const char*)lds + 8192 + wc * 2048 + ql * 64 + sw;

  STG(0, 0);

  for (int kt = 0; kt < nkt; ++kt) {
    const int d = kt & 1;
    const int dOff = d << 12;
    const bool s1 = kt + 1 < nkt;
    if (s1) {
      STG(d ^ 1, kt + 1);
      asm volatile("s_waitcnt vmcnt(2)" ::: "memory");
    } else {
      asm volatile("s_waitcnt vmcnt(0)" ::: "memory");
    }
    __builtin_amdgcn_sched_barrier(0);
    __builtin_amdgcn_s_barrier();
    bf16x8 af[2], bf2[2];
#pragma unroll
    for (int mi = 0; mi < 2; ++mi)
      af[mi] = *(const bf16x8*)(bA + dOff + mi * 1024);
#pragma unroll
    for (int ni = 0; ni < 2; ++ni)
      bf2[ni] = *(const bf16x8*)(bB + dOff + ni * 1024);
    asm volatile("s_waitcnt lgkmcnt(0)" ::: "memory");
    __builtin_amdgcn_sched_barrier(0);
    __builtin_amdgcn_s_setprio(1);
#pragma unroll
    for (int mi = 0; mi < 2; ++mi)
#pragma unroll
      for (int ni = 0; ni < 2; ++ni)
        acc[mi][ni] = __builtin_amdgcn_mfma_f32_16x16x32_bf16(
            bf2[ni], af[mi], acc[mi][ni], 0, 0, 0);
    __builtin_amdgcn_s_setprio(0);
    __builtin_amdgcn_sched_barrier(0);
    __builtin_amdgcn_s_barrier();
    __builtin_amdgcn_sched_barrier(0);
  }
#undef STG

#pragma unroll
  for (int a = 0; a < 2; ++a) {
    const int m = bm + wr * 32 + a * 16 + ql;
#pragma unroll
    for (int c = 0; c < 2; ++c) {
      const int n0 = bn + wc * 32 + c * 16 + g * 4;
      f32x4 v = acc[a][c];
      const float4 b4 = *(const float4*)&bias[n0];
      v[0] += b4.x; v[1] += b4.y; v[2] += b4.z; v[3] += b4.w;
      *(f32x4*)&C[(size_t)m * 1024 + n0] = v;
    }
  }
}

// -------- merged: Plücker lines (bid<256) || V transpose (bid>=256) -----------------
__global__ __launch_bounds__(256) void k_lv(const float* __restrict__ Cs,
                                            const float* __restrict__ Jm,
                                            float* __restrict__ u,
                                            float* __restrict__ rr,
                                            const short* __restrict__ vtmp,
                                            short* __restrict__ vb) {
  __shared__ short tile[64][68];
  const int bid = blockIdx.x;
  if (bid >= 256) {  // vtrans section: 1024 blocks
    const int r2 = bid - 256;
    const int bh = r2 >> 5, b = bh >> 4, h = bh & 15;
    const int t0 = (r2 & 31) * 64;
    const int tid = threadIdx.x;
#pragma unroll
    for (int pass = 0; pass < 16; ++pass) {
      int r = pass * 4 + (tid >> 6);
      int c = tid & 63;
      tile[r][c] = vtmp[((size_t)(b * 2048) + t0 + r) * 1024 + h * 64 + c];
    }
    __syncthreads();
#pragma unroll
    for (int pass = 0; pass < 16; ++pass) {
      int r = pass * 4 + (tid >> 6);
      int c = tid & 63;
      int cp = (c & 32) | (((c >> 2) & 3) << 3) | (((c >> 4) & 1) << 2) | (c & 3);
      vb[(((size_t)b * 16 + h) * 64 + r) * 2048 + t0 + cp] = tile[c][r];
    }
    return;
  }
  int idx = bid * 256 + threadIdx.x;  // [0, 65536)
  int h = idx & 15, t = (idx >> 4) & 2047, b = idx >> 15;
  const float* rowx = Cs + (size_t)(b * 2048 + t) * 272;
  float w1[4], w2[4], r1[4], r2v[4];
  if (t == 0) {
#pragma unroll
    for (int i = 0; i < 4; ++i) w1[i] = 0.f;
  } else {
    const float* prev = Cs + (size_t)(b * 2048 + t - 1) * 272;
#pragma unroll
    for (int i = 0; i < 4; ++i) w1[i] = prev[h * 4 + i];
  }
#pragma unroll
  for (int i = 0; i < 4; ++i) {
    w2[i] = rowx[64 + h * 4 + i];
    r1[i] = rowx[128 + h * 4 + i];
    r2v[i] = rowx[192 + h * 4 + i];
  }
  const int pi[6] = {0, 0, 0, 1, 1, 2}, pj[6] = {1, 2, 3, 2, 3, 3};
  float wl[6], rl[6], nw = 0.f, nr = 0.f;
#pragma unroll
  for (int e = 0; e < 6; ++e) {
    wl[e] = w1[pi[e]] * w2[pj[e]] - w1[pj[e]] * w2[pi[e]];
    rl[e] = r1[pi[e]] * r2v[pj[e]] - r1[pj[e]] * r2v[pi[e]];
    nw += wl[e] * wl[e];
    nr += rl[e] * rl[e];
  }
  nw = 1.f / fmaxf(sqrtf(nw), 1e-12f);
  nr = 1.f / fmaxf(sqrtf(nr), 1e-12f);
  size_t base = (((size_t)b * 16 + h) * 2048 + t) * 6;
#pragma unroll
  for (int jc = 0; jc < 6; ++jc) {
    float s = 0.f;
#pragma unroll
    for (int i = 0; i < 6; ++i) s += wl[i] * Jm[i * 6 + jc];
    u[base + jc] = s * nw;
    rr[base + jc] = rl[jc] * nr;
  }
}

// ---------------- causal flash attention, swapped-operand, UNPAIRED ----------------
// q pre-scaled in GEMM epilogue; exact defer-rescale via __any; max3 trees (T17).
__device__ __forceinline__ void attn_core(const bf16x8 qa[2], f32x4 o[4],
                                          float& m, float& l,
                                          const short* __restrict__ Kc,
                                          const short* __restrict__ Vc,
                                          int qt, int kt, int qglob,
                                          int ql, int g) {
  const int kv0 = kt * 64;
  f32x4 s4[4];
  __builtin_amdgcn_s_setprio(1);
#pragma unroll
  for (int nt = 0; nt < 4; ++nt) {
    int krow = nt * 16 + ql;
    f32x4 s = {0.f, 0.f, 0.f, 0.f};
#pragma unroll
    for (int kc = 0; kc < 2; ++kc) {
      int sl = (kc * 4 + g) ^ (krow & 7);
      bf16x8 af = *(const bf16x8*)&Kc[krow * 64 + sl * 8];
      s = __builtin_amdgcn_mfma_f32_16x16x32_bf16(af, qa[kc], s, 0, 0, 0);
    }
    s4[nt] = s;
  }
  __builtin_amdgcn_s_setprio(0);
  const bool diag = (kt == qt);
  float tv[16];
#pragma unroll
  for (int nt = 0; nt < 4; ++nt)
#pragma unroll
    for (int rg = 0; rg < 4; ++rg) {
      float v = s4[nt][rg];
      if (diag) {
        int kk = kv0 + nt * 16 + g * 4 + rg;
        v = (kk <= qglob) ? v : -1e30f;
      }
      s4[nt][rg] = v;
      tv[nt * 4 + rg] = v;
    }
  // max3-friendly tree (clang fuses fmaxf(fmaxf(a,b),c) -> v_max3_f32)
  float a0 = fmaxf(fmaxf(tv[0], tv[1]), tv[2]);
  float a1 = fmaxf(fmaxf(tv[3], tv[4]), tv[5]);
  float a2 = fmaxf(fmaxf(tv[6], tv[7]), tv[8]);
  float a3 = fmaxf(fmaxf(tv[9], tv[10]), tv[11]);
  float a4 = fmaxf(fmaxf(tv[12], tv[13]), tv[14]);
  float mt = fmaxf(fmaxf(fmaxf(a0, a1), a2), fmaxf(fmaxf(a3, a4), tv[15]));
  mt = fmaxf(mt, __shfl_xor(mt, 16, 64));
  mt = fmaxf(mt, __shfl_xor(mt, 32, 64));
  float mnew = fmaxf(m, mt);
  if (__any(mnew > m)) {  // exact: skip only when sf==1 for all lanes
    float sf = __builtin_amdgcn_exp2f(m - mnew);
    m = mnew;
    l *= sf;
#pragma unroll
    for (int nt = 0; nt < 4; ++nt) o[nt] *= sf;
  }
  float pv[16];
#pragma unroll
  for (int nt = 0; nt < 4; ++nt)
#pragma unroll
    for (int rg = 0; rg < 4; ++rg) {
      float p = __builtin_amdgcn_exp2f(s4[nt][rg] - m);
      s4[nt][rg] = p;
      pv[nt * 4 + rg] = p;
    }
  // pairwise sum tree (depth 4)
  float s01 = pv[0] + pv[1], s23 = pv[2] + pv[3];
  float s45 = pv[4] + pv[5], s67 = pv[6] + pv[7];
  float s89 = pv[8] + pv[9], sab = pv[10] + pv[11];
  float scd = pv[12] + pv[13], sef = pv[14] + pv[15];
  float q0 = s01 + s23, q1 = s45 + s67, q2 = s89 + sab, q3 = scd + sef;
  float rs = (q0 + q1) + (q2 + q3);
  rs += __shfl_xor(rs, 16, 64);
  rs += __shfl_xor(rs, 32, 64);
  l += rs;
  bf16x8 pf[2];
#pragma unroll
  for (int kc = 0; kc < 2; ++kc) {
    u32x4 w;
    w[0] = cvt_pk_bf16(s4[2 * kc][0], s4[2 * kc][1]);
    w[1] = cvt_pk_bf16(s4[2 * kc][2], s4[2 * kc][3]);
    w[2] = cvt_pk_bf16(s4[2 * kc + 1][0], s4[2 * kc + 1][1]);
    w[3] = cvt_pk_bf16(s4[2 * kc + 1][2], s4[2 * kc + 1][3]);
    pf[kc] = __builtin_bit_cast(bf16x8, w);
  }
  __builtin_amdgcn_s_setprio(1);
#pragma unroll
  for (int nt2 = 0; nt2 < 4; ++nt2) {
    int d = nt2 * 16 + ql;
#pragma unroll
    for (int kc = 0; kc < 2; ++kc) {
      int sl = (kc * 4 + g) ^ (d & 7);
      bf16x8 vf = *(const bf16x8*)&Vc[d * 64 + sl * 8];
      o[nt2] = __builtin_amdgcn_mfma_f32_16x16x32_bf16(vf, pf[kc], o[nt2], 0, 0, 0);
    }
  }
  __builtin_amdgcn_s_setprio(0);
}

// epilogue with fused gmean*memval: Fb = bf16(o/l + gm*mvb)
__device__ __forceinline__ void attn_epi(const f32x4 o[4], float l,
                                         short* __restrict__ Fb,
                                         const short* __restrict__ mvb,
                                         const float* __restrict__ gm,
                                         float* ep,
                                         int b, int h, int qt, int wave, int lane) {
  const int ql = lane & 15, g = lane >> 4;
  float inv = 1.f / l;
#pragma unroll
  for (int nt2 = 0; nt2 < 4; ++nt2) {
    f32x4 v = o[nt2] * inv;
    *(f32x4*)&ep[ql * 64 + (((nt2 * 4 + g) ^ (ql & 7)) << 2)] = v;
  }
  const size_t rowbase = ((size_t)b * 2048 + qt * 64 + wave * 16);
  short* srow = Fb + rowbase * 1024 + h * 64;
  const short* mrow = mvb + rowbase * 1024 + h * 64;
  const float* grow = gm + rowbase;
#pragma unroll
  for (int p = 0; p < 8; ++p) {
    int prow = p * 2 + (lane >> 5);
    int d2 = (lane & 31) * 2;
    const float* rp = &ep[prow * 64 + (((d2 >> 2) ^ (prow & 7)) << 2) + (d2 & 3)];
    float2 vv = *(const float2*)rp;
    float gg = grow[prow];
    unsigned mvp = *(const unsigned*)&mrow[(size_t)prow * 1024 + d2];
    float m0 = bf2f((short)(mvp & 0xffff));
    float m1 = bf2f((short)(mvp >> 16));
    *(unsigned*)&srow[(size_t)prow * 1024 + d2] =
        cvt_pk_bf16(vv.x + gg * m0, vv.y + gg * m1);
  }
}

__global__ __launch_bounds__(256, 4) void k_attn(const short* __restrict__ Q,
                                                 const short* __restrict__ Kg,
                                                 const short* __restrict__ Vg,
                                                 const short* __restrict__ mvb,
                                                 const float* __restrict__ gm,
                                                 short* __restrict__ Fb) {
  __shared__ short Kt[2][64 * 64];  // 16KB
  __shared__ short Vt[2][64 * 64];  // 16KB
  const int wg = blockIdx.x;                 // 1024 blocks
  const int x = wg & 7, r = wg >> 3;         // XCD x owns bh in {4x..4x+3}
  const int q = r >> 2, j = r & 3;           // quad-balanced (bh, qt)
  const int bh = 4 * x + j;
  const int q2 = (q + 16) & 31;
  const int qt = (j == 0) ? q : (j == 1) ? 31 - q : (j == 2) ? q2 : 31 - q2;
  const int b = bh >> 4, h = bh & 15;
  const int tid = threadIdx.x;
  const int wave = tid >> 6, lane = tid & 63;
  const int ql = lane & 15, g = lane >> 4;
  const int qglob = qt * 64 + wave * 16 + ql;
  const short* qr = Q + ((size_t)bh * 2048 + qglob) * 64;
  bf16x8 qa[2];
  qa[0] = *(const bf16x8*)&qr[g * 8];
  qa[1] = *(const bf16x8*)&qr[32 + g * 8];
  f32x4 o[4] = {};
  float m = -1e30f, l = 0.f;
  const short* kgb = Kg + (size_t)bh * 2048 * 64;
  const short* vgb = Vg + (size_t)bh * 64 * 2048;

  auto stage = [&](int buf, int kt) {
    int kv0 = kt * 64;
#pragma unroll
    for (int jj = 0; jj < 2; ++jj) {
      int slot = (wave * 2 + jj) * 64 + lane;
      int rr = slot >> 3, s8 = slot & 7;
      int ss = s8 ^ (rr & 7);
      load_lds16(kgb + (size_t)(kv0 + rr) * 64 + ss * 8, &Kt[buf][slot * 8]);
      load_lds16(vgb + (size_t)rr * 2048 + kv0 + ss * 8, &Vt[buf][slot * 8]);
    }
  };

  stage(0, 0);
  int cur = 0;
  for (int it = 0; it <= qt; ++it) {
    __syncthreads();
    if (it < qt) stage(cur ^ 1, it + 1);
    attn_core(qa, o, m, l, Kt[cur], Vt[cur], qt, it, qglob, ql, g);
    cur ^= 1;
  }
  __syncthreads();
  float* ep = (float*)&Kt[0][0] + wave * 1024;  // 16KB scratch across Kt
  attn_epi(o, l, Fb, mvb, gm, ep, b, h, qt, wave, lane);
}

// ------------- decayed prefix scan per channel: w[bh][ch][t] = S_t[p][q] -------------
__global__ __launch_bounds__(256) void k_scanw(const float* __restrict__ u,
                                               float* __restrict__ w,
                                               const float* __restrict__ decays) {
  __shared__ float wtot[4];
  const int ch = blockIdx.x;
  const int bh = blockIdx.y;
  const float d = decays[bh & 15];
  const int p = ch / 6, q = ch % 6;
  const int tid = threadIdx.x, lane = tid & 63, wv = tid >> 6;
  const float* ub = u + (size_t)bh * 2048 * 6;
  const int t0 = tid * 8;
  float z[8];
  float a = 0.f;
#pragma unroll
  for (int i = 0; i < 8; ++i) {
    float up = ub[(t0 + i) * 6 + p], uq = ub[(t0 + i) * 6 + q];
    z[i] = up * uq;
    a = d * (a + z[i]);
  }
  float d8 = d * d; d8 *= d8; d8 *= d8;
  float I = a;
  float ds = d8;
#pragma unroll
  for (int s = 1; s < 64; s <<= 1) {
    float v = __shfl_up(I, s, 64);
    if (lane >= s) I += ds * v;
    ds *= ds;
  }
  if (lane == 63) wtot[wv] = I;
  __syncthreads();
  float carry = 0.f;
  for (int w2 = 0; w2 < wv; ++w2) carry = carry * ds + wtot[w2];
  float dlp1 = exp2f(log2f(d8) * (float)(lane + 1));
  float Ig = I + dlp1 * carry;
  float E = __shfl_up(Ig, 1, 64);
  if (lane == 0) E = carry;
  float S = E;
  float out[8];
#pragma unroll
  for (int i = 0; i < 8; ++i) {
    out[i] = S;
    S = d * (S + z[i]);
  }
  float4* wp = (float4*)(w + ((size_t)bh * 36 + ch) * 2048 + t0);
  wp[0] = make_float4(out[0], out[1], out[2], out[3]);
  wp[1] = make_float4(out[4], out[5], out[6], out[7]);
}

// ---- scandot + per-h gate term: a[bh][t] = sig(score*scale_h) * sig(memg logit) ----
__global__ __launch_bounds__(256) void k_scandot(const float* __restrict__ rr,
                                                 const float* __restrict__ w,
                                                 const float* __restrict__ Cs,
                                                 const float* __restrict__ memg_b,
                                                 const float* __restrict__ mem_scale,
                                                 float* __restrict__ aout) {
  const int bh = blockIdx.y;
  const int b = bh >> 4, h = bh & 15;
  const int t = blockIdx.x * 256 + threadIdx.x;
  const float* rb = rr + ((size_t)bh * 2048 + t) * 6;
  float r[6];
#pragma unroll
  for (int i = 0; i < 6; ++i) r[i] = rb[i];
  const float* wb = w + (size_t)bh * 36 * 2048 + t;
  float s = 0.f;
#pragma unroll
  for (int ch = 0; ch < 36; ++ch)
    s += r[ch / 6] * r[ch % 6] * wb[(size_t)ch * 2048];
  float gl = Cs[(size_t)(b * 2048 + t) * 272 + 256 + h] + memg_b[h];
  float a = 1.f / (1.f + __expf(-s * mem_scale[h]));
  float gg = 1.f / (1.f + __expf(-gl));
  aout[(size_t)bh * 2048 + t] = a * gg;
}

// ---------------- gate: gmean[b,t] = mean_h a[bh][t] ----------------
__global__ __launch_bounds__(256) void k_gate(const float* __restrict__ aout,
                                              float* __restrict__ gmean) {
  int idx = blockIdx.x * 256 + threadIdx.x;
  if (idx >= BT) return;
  int b = idx >> 11, t = idx & 2047;
  float acc = 0.f;
#pragma unroll
  for (int h = 0; h < 16; ++h)
    acc += aout[((size_t)(b * 16 + h) * 2048) + t];
  gmean[idx] = acc * (1.f / 16.f);
}

extern "C" void kernel_launch(void* const* d_in, const int* in_sizes, int n_in,
                              void* d_out, int out_size, void* d_ws, size_t ws_size,
                              hipStream_t stream) {
  const float* x = (const float*)d_in[0];
  const float* qkv_w = (const float*)d_in[1];
  const float* qkv_b = (const float*)d_in[2];
  const float* w1w = (const float*)d_in[3];
  const float* w2w = (const float*)d_in[4];
  const float* w1r = (const float*)d_in[5];
  const float* w2r = (const float*)d_in[6];
  const float* memv_w = (const float*)d_in[7];
  const float* memv_b = (const float*)d_in[8];
  const float* memg_w = (const float*)d_in[9];
  const float* memg_b = (const float*)d_in[10];
  const float* mem_scale = (const float*)d_in[11];
  const float* out_w = (const float*)d_in[12];
  const float* out_b = (const float*)d_in[13];
  const float* Jm = (const float*)d_in[14];
  const float* decays = (const float*)d_in[15];

  char* w = (char*)d_ws;
  size_t off = 0;
  auto alloc = [&](size_t bytes) -> void* {
    void* p = w + off;
    off += (bytes + 255) & ~(size_t)255;
    return p;
  };
  short* xb = (short*)alloc((size_t)BT * Dd * 2);
  short* WTall = (short*)alloc((size_t)4480 * 1024 * 2);  // qkv|memv|sm
  short* WTout = (short*)alloc((size_t)1024 * 1024 * 2);
  short* qb = (short*)alloc((size_t)32 * 2048 * 64 * 2);
  short* kb = (short*)alloc((size_t)32 * 2048 * 64 * 2);
  short* vtmp = (short*)alloc((size_t)BT * 1024 * 2);
  short* vb = (short*)alloc((size_t)32 * 64 * 2048 * 2);
  float* Csm = (float*)alloc((size_t)BT * 272 * 4);
  float* ua = (float*)alloc((size_t)32 * 2048 * 6 * 4);
  float* ra = (float*)alloc((size_t)32 * 2048 * 6 * 4);
  float* sc = (float*)alloc((size_t)32 * 2048 * 4);
  float* gm = (float*)alloc((size_t)BT * 4);
  short* mvb = (short*)alloc((size_t)BT * 1024 * 2);
  short* Fb = (short*)alloc((size_t)BT * Dd * 2);
  float* wscan = (float*)alloc((size_t)32 * 36 * 2048 * 4);
  (void)ws_size; (void)in_sizes; (void)n_in; (void)out_size;

  // prep: all weight transposes + x->bf16 in ONE launch
  k_wtall<<<5456, 256, 0, stream>>>(qkv_w, memv_w, out_w, w1w, w2w, w1r, w2r,
                                    memg_w, WTall, WTout, x, xb);

  // fused GEMM: qkv (q pre-scaled) | memv->bf16 | sm->Csm over N=4480, 4 blocks/CU
  k_g128<<<1120, 256, 0, stream>>>(xb, WTall, qkv_b, memv_b,
                                   qb, kb, vtmp, mvb, Csm, 1024);

  // lines (256 blocks) || vtrans (1024 blocks) in one launch
  k_lv<<<1280, 256, 0, stream>>>(Csm, Jm, ua, ra, vtmp, vb);

  // decay scan + scandot(+per-h gate term) + 16-mean
  k_scanw<<<dim3(36, 32), 256, 0, stream>>>(ua, wscan, decays);
  k_scandot<<<dim3(8, 32), 256, 0, stream>>>(ra, wscan, Csm, memg_b, mem_scale, sc);
  k_gate<<<(BT + 255) / 256, 256, 0, stream>>>(sc, gm);

  // attention (epilogue fuses + gm*mvb -> Fb): 1024 blocks, 4/CU, quad-balanced
  k_attn<<<1024, 256, 0, stream>>>(qb, kb, vb, mvb, gm, Fb);

  // final GEMM: 64x64-tile full-K, fp32 + bias -> d_out, grid 1024 (4/CU)
  k_gout<<<1024, 256, 0, stream>>>(Fb, WTout, out_b, (float*)d_out, 1024);
}

// Round 23
// 152.441 us; speedup vs baseline: 1.0659x; 1.0014x over previous
//
#include <hip/hip_runtime.h>

#define BT 4096      // B*T
#define Dd 1024
#define Tt 2048
#define ATT_SCALE 0.18033688f  // 0.125 * log2(e)

typedef __attribute__((ext_vector_type(8))) short bf16x8;
typedef __attribute__((ext_vector_type(4))) float f32x4;
typedef __attribute__((ext_vector_type(4))) unsigned u32x4;

__device__ __forceinline__ short f2bf(float f) {
  unsigned u = __builtin_bit_cast(unsigned, f);
  u = (u + 0x7FFFu + ((u >> 16) & 1u)) >> 16;
  return (short)u;
}
__device__ __forceinline__ float bf2f(short s) {
  unsigned u = ((unsigned)(unsigned short)s) << 16;
  return __builtin_bit_cast(float, u);
}
__device__ __forceinline__ unsigned cvt_pk_bf16(float a, float b) {
  unsigned r;
  asm("v_cvt_pk_bf16_f32 %0, %1, %2" : "=v"(r) : "v"(a), "v"(b));
  return r;
}

__device__ __forceinline__ void load_lds16(const void* gsrc, void* ldst) {
  __builtin_amdgcn_global_load_lds(
      (const __attribute__((address_space(1))) void*)gsrc,
      (__attribute__((address_space(3))) void*)ldst, 16, 0, 0);
}

// --- merged prep: weight transposes (sections 0..1359) + x fp32->bf16 (1360..5455) --
__global__ __launch_bounds__(256) void k_wtall(
    const float* __restrict__ qkv_w, const float* __restrict__ memv_w,
    const float* __restrict__ out_w, const float* __restrict__ w1w,
    const float* __restrict__ w2w, const float* __restrict__ w1r,
    const float* __restrict__ w2r, const float* __restrict__ memg_w,
    short* __restrict__ WTall, short* __restrict__ WTout,
    const float* __restrict__ x, short* __restrict__ xb) {
  __shared__ float tile[64][65];
  const int bid = blockIdx.x;
  if (bid >= 1360) {  // cvt section: 4096 blocks x 256 float4
    int i = (bid - 1360) * 256 + threadIdx.x;
    float4 v = ((const float4*)x)[i];
    short4 o;
    o.x = f2bf(v.x); o.y = f2bf(v.y); o.z = f2bf(v.z); o.w = f2bf(v.w);
    ((short4*)xb)[i] = o;
    return;
  }
  const float* src;
  short* dst;
  int N, n0, k0, rowoff;
  if (bid < 768) {
    src = qkv_w; dst = WTall; N = 3072;
    n0 = (bid % 48) * 64; k0 = (bid / 48) * 64; rowoff = 0;
  } else if (bid < 1024) {
    int r = bid - 768;
    src = memv_w; dst = WTall; N = 1024;
    n0 = (r % 16) * 64; k0 = (r / 16) * 64; rowoff = 3072;
  } else if (bid < 1280) {
    int r = bid - 1024;
    src = out_w; dst = WTout; N = 1024;
    n0 = (r % 16) * 64; k0 = (r / 16) * 64; rowoff = 0;
  } else {
    int r = bid - 1280;
    int z = r / 16;
    src = z == 0 ? w1w : z == 1 ? w2w : z == 2 ? w1r : z == 3 ? w2r : memg_w;
    dst = WTall; N = (z == 4) ? 16 : 64;
    n0 = 0; k0 = (r % 16) * 64; rowoff = 4096 + z * 64;
  }
  const int c = threadIdx.x & 63, r4 = threadIdx.x >> 6;
#pragma unroll
  for (int i = 0; i < 16; ++i) {
    int r = i * 4 + r4;
    float v = 0.f;
    if (n0 + c < N) v = src[(size_t)(k0 + r) * N + n0 + c];
    tile[r][c] = v;
  }
  __syncthreads();
#pragma unroll
  for (int i = 0; i < 16; ++i) {
    int n = i * 4 + r4;
    if (n0 + n < N)
      dst[(size_t)(rowoff + n0 + n) * 1024 + k0 + c] = f2bf(tile[c][n]);
  }
}

// ====== 128x128 GEMM, BK=32 dbuf (32KB -> 4 blocks/CU), counted-vmcnt schedule =====
// q-range outputs are pre-scaled by ATT_SCALE (folds attention's softmax scale).
// sched_barrier pins only where mandatory (post-lgkm; pre-barrier after vmcnt) —
// the MFMA tail may sink past the bottom barrier and overlap the next STG issue.
__global__ __launch_bounds__(256, 4) void k_g128(
    const short* __restrict__ A, const short* __restrict__ Bt,
    const float* __restrict__ bias, const float* __restrict__ bias2,
    short* __restrict__ oq, short* __restrict__ ok_, short* __restrict__ ov,
    short* __restrict__ omv, float* __restrict__ ocs, int K) {
  __shared__ __align__(16) short lds[16384];  // 32 KiB
  const int tid = threadIdx.x;
  const int wid = tid >> 6, lane = tid & 63;
  const int wr = wid >> 1, wc = wid & 1;
  const int ql = lane & 15, g = lane >> 4;
  int wg = blockIdx.x, xcd = wg & 7, idx = wg >> 3;
  const int n_t = idx >> 2;
  const int m_t = xcd * 4 + (idx & 3);
  const int nkt = K >> 5;
  const int bm = m_t * 128, bn = n_t * 128;
  f32x4 acc[4][4] = {};

  const short* srcA[2];
  const short* srcB[2];
  short* dstA[2];
  short* dstB[2];
#pragma unroll
  for (int j = 0; j < 2; ++j) {
    int o16 = j * 256 + tid;
    int rr = o16 >> 2, u = o16 & 3;
    int sp = u ^ ((rr >> 1) & 3);
    srcA[j] = A + (size_t)(bm + rr) * K + sp * 8;
    srcB[j] = Bt + (size_t)(bn + rr) * K + sp * 8;
    dstA[j] = lds + o16 * 8;
    dstB[j] = lds + 8192 + o16 * 8;
  }
#define STG(D, KT)                                                            \
  do {                                                                        \
    const int k0s = (KT) << 5;                                                \
    _Pragma("unroll") for (int j = 0; j < 2; ++j) {                           \
      load_lds16(srcA[j] + k0s, dstA[j] + (D)*4096);                          \
      load_lds16(srcB[j] + k0s, dstB[j] + (D)*4096);                          \
    }                                                                         \
  } while (0)

  const int sw = (g ^ ((ql >> 1) & 3)) << 4;
  const char* bA = (const char*)lds + wr * 4096 + ql * 64 + sw;
  const char* bB = (const char*)lds + 16384 + wc * 4096 + ql * 64 + sw;

#define RD_A(DST, DOFF, MQ)                                                    \
  _Pragma("unroll") for (int mi = 0; mi < 2; ++mi)                             \
      DST[mi] = *(const bf16x8*)(bA + (DOFF) + (MQ)*2048 + mi * 1024);
#define RD_B(DST, DOFF, NQ)                                                    \
  _Pragma("unroll") for (int ni = 0; ni < 2; ++ni)                             \
      DST[ni] = *(const bf16x8*)(bB + (DOFF) + (NQ)*2048 + ni * 1024);
#define MFMA4(AF, BF, MQ, NQ)                                                  \
  _Pragma("unroll") for (int mi = 0; mi < 2; ++mi)                             \
      _Pragma("unroll") for (int ni = 0; ni < 2; ++ni)                         \
          acc[(MQ)*2 + mi][(NQ)*2 + ni] =                                      \
      __builtin_amdgcn_mfma_f32_16x16x32_bf16(                                 \
          BF[ni], AF[mi], acc[(MQ)*2 + mi][(NQ)*2 + ni], 0, 0, 0)

  STG(0, 0);

  for (int kt = 0; kt < nkt; ++kt) {
    const int d = kt & 1;
    const int dOff = d << 13;
    const bool s1 = kt + 1 < nkt;
    if (s1) {
      STG(d ^ 1, kt + 1);
      asm volatile("s_waitcnt vmcnt(4)" ::: "memory");
    } else {
      asm volatile("s_waitcnt vmcnt(0)" ::: "memory");
    }
    __builtin_amdgcn_sched_barrier(0);  // keep vmcnt wait ordered before barrier
    __builtin_amdgcn_s_barrier();       // all waves' kt data visible
    bf16x8 a0[2], a1[2], b0[2], b1[2];
    RD_A(a0, dOff, 0);
    RD_A(a1, dOff, 1);
    RD_B(b0, dOff, 0);
    RD_B(b1, dOff, 1);
    asm volatile("s_waitcnt lgkmcnt(0)" ::: "memory");
    __builtin_amdgcn_sched_barrier(0);  // rule #18: MFMA must not hoist above
    __builtin_amdgcn_s_setprio(1);
    MFMA4(a0, b0, 0, 0);
    MFMA4(a0, b1, 0, 1);
    MFMA4(a1, b1, 1, 1);
    MFMA4(a1, b0, 1, 0);
    __builtin_amdgcn_s_setprio(0);
    __builtin_amdgcn_s_barrier();       // fence kt LDS reads vs kt+1 stage (no pins:
                                        // reg-only MFMA tail may sink past)
  }
#undef MFMA4
#undef RD_A
#undef RD_B
#undef STG

#pragma unroll
  for (int a = 0; a < 4; ++a) {
    const int m = bm + wr * 64 + a * 16 + ql;
    const int b = m >> 11, t = m & 2047;
#pragma unroll
    for (int c = 0; c < 4; ++c) {
      const int n0 = bn + wc * 64 + c * 16 + g * 4;
      f32x4 v = acc[a][c];
      if (n0 < 3072) {
        const float4 b4 = *(const float4*)&bias[n0];
        v[0] += b4.x; v[1] += b4.y; v[2] += b4.z; v[3] += b4.w;
        const int sel = n0 >> 10, rem = n0 & 1023;
        if (sel == 0) {
          v[0] *= ATT_SCALE; v[1] *= ATT_SCALE; v[2] *= ATT_SCALE; v[3] *= ATT_SCALE;
          uint2 pk = make_uint2(cvt_pk_bf16(v[0], v[1]), cvt_pk_bf16(v[2], v[3]));
          *(uint2*)&oq[((size_t)(b * 16 + (rem >> 6)) * 2048 + t) * 64 + (rem & 63)] = pk;
        } else if (sel == 1) {
          uint2 pk = make_uint2(cvt_pk_bf16(v[0], v[1]), cvt_pk_bf16(v[2], v[3]));
          *(uint2*)&ok_[((size_t)(b * 16 + (rem >> 6)) * 2048 + t) * 64 + (rem & 63)] = pk;
        } else {
          uint2 pk = make_uint2(cvt_pk_bf16(v[0], v[1]), cvt_pk_bf16(v[2], v[3]));
          *(uint2*)&ov[(size_t)(b * 2048 + t) * 1024 + rem] = pk;
        }
      } else if (n0 < 4096) {
        const float4 b4 = *(const float4*)&bias2[n0 - 3072];
        v[0] += b4.x; v[1] += b4.y; v[2] += b4.z; v[3] += b4.w;
        uint2 pk = make_uint2(cvt_pk_bf16(v[0], v[1]), cvt_pk_bf16(v[2], v[3]));
        *(uint2*)&omv[(size_t)(b * 2048 + t) * 1024 + n0 - 3072] = pk;
      } else if (n0 < 4368) {
        *(f32x4*)&ocs[(size_t)(b * 2048 + t) * 272 + n0 - 4096] = v;
      }
    }
  }
}

// ====== out-GEMM: 64x64, BK=32 dbuf (16KB), counted vmcnt(2), grid 1024 (4/CU) =====
__global__ __launch_bounds__(256, 4) void k_gout(
    const short* __restrict__ A, const short* __restrict__ Bt,
    const float* __restrict__ bias, float* __restrict__ C, int K) {
  __shared__ __align__(16) short lds[8192];  // 16 KiB
  const int tid = threadIdx.x;
  const int wid = tid >> 6, lane = tid & 63;
  const int wr = wid >> 1, wc = wid & 1;
  const int ql = lane & 15, g = lane >> 4;
  int wg = blockIdx.x, xcd = wg & 7, idx = wg >> 3;
  const int n_t = idx >> 3, m_t = xcd * 8 + (idx & 7);
  const int bm = m_t * 64, bn = n_t * 64;
  const int nkt = K >> 5;
  f32x4 acc[2][2] = {};

  const short* srcA;
  const short* srcB;
  short* dstA;
  short* dstB;
  {
    int rr = tid >> 2, u = tid & 3;
    int sp = u ^ ((rr >> 1) & 3);
    srcA = A + (size_t)(bm + rr) * K + sp * 8;
    srcB = Bt + (size_t)(bn + rr) * K + sp * 8;
    dstA = lds + tid * 8;
    dstB = lds + 4096 + tid * 8;
  }
#define STG(D, KT)                                                            \
  do {                                                                        \
    const int k0s = (KT) << 5;                                                \
    load_lds16(srcA + k0s, dstA + (D)*2048);                                  \
    load_lds16(srcB + k0s, dstB + (D)*2048);                                  \
  } while (0)

  const int sw = (g ^ ((ql >> 1) & 3)) << 4;
  const char* bA = (const char*)lds + wr * 2048 + ql * 64 + sw;
  const char* bB = (const char*)lds + 8192 + wc * 2048 + ql * 64 + sw;

  STG(0, 0);

  for (int kt = 0; kt < nkt; ++kt) {
    const int d = kt & 1;
    const int dOff = d << 12;
    const bool s1 = kt + 1 < nkt;
    if (s1) {
      STG(d ^ 1, kt + 1);
      asm volatile("s_waitcnt vmcnt(2)" ::: "memory");
    } else {
      asm volatile("s_waitcnt vmcnt(0)" ::: "memory");
    }
    __builtin_amdgcn_sched_barrier(0);
    __builtin_amdgcn_s_barrier();
    bf16x8 af[2], bf2[2];
#pragma unroll
    for (int mi = 0; mi < 2; ++mi)
      af[mi] = *(const bf16x8*)(bA + dOff + mi * 1024);
#pragma unroll
    for (int ni = 0; ni < 2; ++ni)
      bf2[ni] = *(const bf16x8*)(bB + dOff + ni * 1024);
    asm volatile("s_waitcnt lgkmcnt(0)" ::: "memory");
    __builtin_amdgcn_sched_barrier(0);
    __builtin_amdgcn_s_setprio(1);
#pragma unroll
    for (int mi = 0; mi < 2; ++mi)
#pragma unroll
      for (int ni = 0; ni < 2; ++ni)
        acc[mi][ni] = __builtin_amdgcn_mfma_f32_16x16x32_bf16(
            bf2[ni], af[mi], acc[mi][ni], 0, 0, 0);
    __builtin_amdgcn_s_setprio(0);
    __builtin_amdgcn_s_barrier();
  }
#undef STG

#pragma unroll
  for (int a = 0; a < 2; ++a) {
    const int m = bm + wr * 32 + a * 16 + ql;
#pragma unroll
    for (int c = 0; c < 2; ++c) {
      const int n0 = bn + wc * 32 + c * 16 + g * 4;
      f32x4 v = acc[a][c];
      const float4 b4 = *(const float4*)&bias[n0];
      v[0] += b4.x; v[1] += b4.y; v[2] += b4.z; v[3] += b4.w;
      *(f32x4*)&C[(size_t)m * 1024 + n0] = v;
    }
  }
}

// -------- merged: Plücker lines (bid<256) || V transpose (bid>=256) -----------------
__global__ __launch_bounds__(256) void k_lv(const float* __restrict__ Cs,
                                            const float* __restrict__ Jm,
                                            float* __restrict__ u,
                                            float* __restrict__ rr,
                                            const short* __restrict__ vtmp,
                                            short* __restrict__ vb) {
  __shared__ short tile[64][68];
  const int bid = blockIdx.x;
  if (bid >= 256) {  // vtrans section: 1024 blocks
    const int r2 = bid - 256;
    const int bh = r2 >> 5, b = bh >> 4, h = bh & 15;
    const int t0 = (r2 & 31) * 64;
    const int tid = threadIdx.x;
#pragma unroll
    for (int pass = 0; pass < 16; ++pass) {
      int r = pass * 4 + (tid >> 6);
      int c = tid & 63;
      tile[r][c] = vtmp[((size_t)(b * 2048) + t0 + r) * 1024 + h * 64 + c];
    }
    __syncthreads();
#pragma unroll
    for (int pass = 0; pass < 16; ++pass) {
      int r = pass * 4 + (tid >> 6);
      int c = tid & 63;
      int cp = (c & 32) | (((c >> 2) & 3) << 3) | (((c >> 4) & 1) << 2) | (c & 3);
      vb[(((size_t)b * 16 + h) * 64 + r) * 2048 + t0 + cp] = tile[c][r];
    }
    return;
  }
  int idx = bid * 256 + threadIdx.x;  // [0, 65536)
  int h = idx & 15, t = (idx >> 4) & 2047, b = idx >> 15;
  const float* rowx = Cs + (size_t)(b * 2048 + t) * 272;
  float w1[4], w2[4], r1[4], r2v[4];
  if (t == 0) {
#pragma unroll
    for (int i = 0; i < 4; ++i) w1[i] = 0.f;
  } else {
    const float* prev = Cs + (size_t)(b * 2048 + t - 1) * 272;
#pragma unroll
    for (int i = 0; i < 4; ++i) w1[i] = prev[h * 4 + i];
  }
#pragma unroll
  for (int i = 0; i < 4; ++i) {
    w2[i] = rowx[64 + h * 4 + i];
    r1[i] = rowx[128 + h * 4 + i];
    r2v[i] = rowx[192 + h * 4 + i];
  }
  const int pi[6] = {0, 0, 0, 1, 1, 2}, pj[6] = {1, 2, 3, 2, 3, 3};
  float wl[6], rl[6], nw = 0.f, nr = 0.f;
#pragma unroll
  for (int e = 0; e < 6; ++e) {
    wl[e] = w1[pi[e]] * w2[pj[e]] - w1[pj[e]] * w2[pi[e]];
    rl[e] = r1[pi[e]] * r2v[pj[e]] - r1[pj[e]] * r2v[pi[e]];
    nw += wl[e] * wl[e];
    nr += rl[e] * rl[e];
  }
  nw = 1.f / fmaxf(sqrtf(nw), 1e-12f);
  nr = 1.f / fmaxf(sqrtf(nr), 1e-12f);
  size_t base = (((size_t)b * 16 + h) * 2048 + t) * 6;
#pragma unroll
  for (int jc = 0; jc < 6; ++jc) {
    float s = 0.f;
#pragma unroll
    for (int i = 0; i < 6; ++i) s += wl[i] * Jm[i * 6 + jc];
    u[base + jc] = s * nw;
    rr[base + jc] = rl[jc] * nr;
  }
}

// ---------------- causal flash attention, swapped-operand, UNPAIRED ----------------
// q pre-scaled in GEMM epilogue; exact defer-rescale via __any; max3 trees (T17).
__device__ __forceinline__ void attn_core(const bf16x8 qa[2], f32x4 o[4],
                                          float& m, float& l,
                                          const short* __restrict__ Kc,
                                          const short* __restrict__ Vc,
                                          int qt, int kt, int qglob,
                                          int ql, int g) {
  const int kv0 = kt * 64;
  f32x4 s4[4];
  __builtin_amdgcn_s_setprio(1);
#pragma unroll
  for (int nt = 0; nt < 4; ++nt) {
    int krow = nt * 16 + ql;
    f32x4 s = {0.f, 0.f, 0.f, 0.f};
#pragma unroll
    for (int kc = 0; kc < 2; ++kc) {
      int sl = (kc * 4 + g) ^ (krow & 7);
      bf16x8 af = *(const bf16x8*)&Kc[krow * 64 + sl * 8];
      s = __builtin_amdgcn_mfma_f32_16x16x32_bf16(af, qa[kc], s, 0, 0, 0);
    }
    s4[nt] = s;
  }
  __builtin_amdgcn_s_setprio(0);
  const bool diag = (kt == qt);
  float tv[16];
#pragma unroll
  for (int nt = 0; nt < 4; ++nt)
#pragma unroll
    for (int rg = 0; rg < 4; ++rg) {
      float v = s4[nt][rg];
      if (diag) {
        int kk = kv0 + nt * 16 + g * 4 + rg;
        v = (kk <= qglob) ? v : -1e30f;
      }
      s4[nt][rg] = v;
      tv[nt * 4 + rg] = v;
    }
  float a0 = fmaxf(fmaxf(tv[0], tv[1]), tv[2]);
  float a1 = fmaxf(fmaxf(tv[3], tv[4]), tv[5]);
  float a2 = fmaxf(fmaxf(tv[6], tv[7]), tv[8]);
  float a3 = fmaxf(fmaxf(tv[9], tv[10]), tv[11]);
  float a4 = fmaxf(fmaxf(tv[12], tv[13]), tv[14]);
  float mt = fmaxf(fmaxf(fmaxf(a0, a1), a2), fmaxf(fmaxf(a3, a4), tv[15]));
  mt = fmaxf(mt, __shfl_xor(mt, 16, 64));
  mt = fmaxf(mt, __shfl_xor(mt, 32, 64));
  float mnew = fmaxf(m, mt);
  if (__any(mnew > m)) {  // exact: skip only when sf==1 for all lanes
    float sf = __builtin_amdgcn_exp2f(m - mnew);
    m = mnew;
    l *= sf;
#pragma unroll
    for (int nt = 0; nt < 4; ++nt) o[nt] *= sf;
  }
  float pv[16];
#pragma unroll
  for (int nt = 0; nt < 4; ++nt)
#pragma unroll
    for (int rg = 0; rg < 4; ++rg) {
      float p = __builtin_amdgcn_exp2f(s4[nt][rg] - m);
      s4[nt][rg] = p;
      pv[nt * 4 + rg] = p;
    }
  float s01 = pv[0] + pv[1], s23 = pv[2] + pv[3];
  float s45 = pv[4] + pv[5], s67 = pv[6] + pv[7];
  float s89 = pv[8] + pv[9], sab = pv[10] + pv[11];
  float scd = pv[12] + pv[13], sef = pv[14] + pv[15];
  float q0 = s01 + s23, q1 = s45 + s67, q2 = s89 + sab, q3 = scd + sef;
  float rs = (q0 + q1) + (q2 + q3);
  rs += __shfl_xor(rs, 16, 64);
  rs += __shfl_xor(rs, 32, 64);
  l += rs;
  bf16x8 pf[2];
#pragma unroll
  for (int kc = 0; kc < 2; ++kc) {
    u32x4 w;
    w[0] = cvt_pk_bf16(s4[2 * kc][0], s4[2 * kc][1]);
    w[1] = cvt_pk_bf16(s4[2 * kc][2], s4[2 * kc][3]);
    w[2] = cvt_pk_bf16(s4[2 * kc + 1][0], s4[2 * kc + 1][1]);
    w[3] = cvt_pk_bf16(s4[2 * kc + 1][2], s4[2 * kc + 1][3]);
    pf[kc] = __builtin_bit_cast(bf16x8, w);
  }
  __builtin_amdgcn_s_setprio(1);
#pragma unroll
  for (int nt2 = 0; nt2 < 4; ++nt2) {
    int d = nt2 * 16 + ql;
#pragma unroll
    for (int kc = 0; kc < 2; ++kc) {
      int sl = (kc * 4 + g) ^ (d & 7);
      bf16x8 vf = *(const bf16x8*)&Vc[d * 64 + sl * 8];
      o[nt2] = __builtin_amdgcn_mfma_f32_16x16x32_bf16(vf, pf[kc], o[nt2], 0, 0, 0);
    }
  }
  __builtin_amdgcn_s_setprio(0);
}

// epilogue with fused gmean*memval: Fb = bf16(o/l + gm*mvb)
__device__ __forceinline__ void attn_epi(const f32x4 o[4], float l,
                                         short* __restrict__ Fb,
                                         const short* __restrict__ mvb,
                                         const float* __restrict__ gm,
                                         float* ep,
                                         int b, int h, int qt, int wave, int lane) {
  const int ql = lane & 15, g = lane >> 4;
  float inv = 1.f / l;
#pragma unroll
  for (int nt2 = 0; nt2 < 4; ++nt2) {
    f32x4 v = o[nt2] * inv;
    *(f32x4*)&ep[ql * 64 + (((nt2 * 4 + g) ^ (ql & 7)) << 2)] = v;
  }
  const size_t rowbase = ((size_t)b * 2048 + qt * 64 + wave * 16);
  short* srow = Fb + rowbase * 1024 + h * 64;
  const short* mrow = mvb + rowbase * 1024 + h * 64;
  const float* grow = gm + rowbase;
#pragma unroll
  for (int p = 0; p < 8; ++p) {
    int prow = p * 2 + (lane >> 5);
    int d2 = (lane & 31) * 2;
    const float* rp = &ep[prow * 64 + (((d2 >> 2) ^ (prow & 7)) << 2) + (d2 & 3)];
    float2 vv = *(const float2*)rp;
    float gg = grow[prow];
    unsigned mvp = *(const unsigned*)&mrow[(size_t)prow * 1024 + d2];
    float m0 = bf2f((short)(mvp & 0xffff));
    float m1 = bf2f((short)(mvp >> 16));
    *(unsigned*)&srow[(size_t)prow * 1024 + d2] =
        cvt_pk_bf16(vv.x + gg * m0, vv.y + gg * m1);
  }
}

__global__ __launch_bounds__(256, 4) void k_attn(const short* __restrict__ Q,
                                                 const short* __restrict__ Kg,
                                                 const short* __restrict__ Vg,
                                                 const short* __restrict__ mvb,
                                                 const float* __restrict__ gm,
                                                 short* __restrict__ Fb) {
  __shared__ short Kt[2][64 * 64];  // 16KB
  __shared__ short Vt[2][64 * 64];  // 16KB
  const int wg = blockIdx.x;                 // 1024 blocks
  const int x = wg & 7, r = wg >> 3;         // XCD x owns bh in {4x..4x+3}
  const int q = r >> 2, j = r & 3;           // quad-balanced (bh, qt)
  const int bh = 4 * x + j;
  const int q2 = (q + 16) & 31;
  const int qt = (j == 0) ? q : (j == 1) ? 31 - q : (j == 2) ? q2 : 31 - q2;
  const int b = bh >> 4, h = bh & 15;
  const int tid = threadIdx.x;
  const int wave = tid >> 6, lane = tid & 63;
  const int ql = lane & 15, g = lane >> 4;
  const int qglob = qt * 64 + wave * 16 + ql;
  const short* qr = Q + ((size_t)bh * 2048 + qglob) * 64;
  bf16x8 qa[2];
  qa[0] = *(const bf16x8*)&qr[g * 8];
  qa[1] = *(const bf16x8*)&qr[32 + g * 8];
  f32x4 o[4] = {};
  float m = -1e30f, l = 0.f;
  const short* kgb = Kg + (size_t)bh * 2048 * 64;
  const short* vgb = Vg + (size_t)bh * 64 * 2048;

  auto stage = [&](int buf, int kt) {
    int kv0 = kt * 64;
#pragma unroll
    for (int jj = 0; jj < 2; ++jj) {
      int slot = (wave * 2 + jj) * 64 + lane;
      int rr = slot >> 3, s8 = slot & 7;
      int ss = s8 ^ (rr & 7);
      load_lds16(kgb + (size_t)(kv0 + rr) * 64 + ss * 8, &Kt[buf][slot * 8]);
      load_lds16(vgb + (size_t)rr * 2048 + kv0 + ss * 8, &Vt[buf][slot * 8]);
    }
  };

  stage(0, 0);
  int cur = 0;
  for (int it = 0; it <= qt; ++it) {
    __syncthreads();
    if (it < qt) stage(cur ^ 1, it + 1);
    attn_core(qa, o, m, l, Kt[cur], Vt[cur], qt, it, qglob, ql, g);
    cur ^= 1;
  }
  __syncthreads();
  float* ep = (float*)&Kt[0][0] + wave * 1024;  // 16KB scratch across Kt
  attn_epi(o, l, Fb, mvb, gm, ep, b, h, qt, wave, lane);
}

// ------------- decayed prefix scan per channel: w[bh][ch][t] = S_t[p][q] -------------
__global__ __launch_bounds__(256) void k_scanw(const float* __restrict__ u,
                                               float* __restrict__ w,
                                               const float* __restrict__ decays) {
  __shared__ float wtot[4];
  const int ch = blockIdx.x;
  const int bh = blockIdx.y;
  const float d = decays[bh & 15];
  const int p = ch / 6, q = ch % 6;
  const int tid = threadIdx.x, lane = tid & 63, wv = tid >> 6;
  const float* ub = u + (size_t)bh * 2048 * 6;
  const int t0 = tid * 8;
  float z[8];
  float a = 0.f;
#pragma unroll
  for (int i = 0; i < 8; ++i) {
    float up = ub[(t0 + i) * 6 + p], uq = ub[(t0 + i) * 6 + q];
    z[i] = up * uq;
    a = d * (a + z[i]);
  }
  float d8 = d * d; d8 *= d8; d8 *= d8;
  float I = a;
  float ds = d8;
#pragma unroll
  for (int s = 1; s < 64; s <<= 1) {
    float v = __shfl_up(I, s, 64);
    if (lane >= s) I += ds * v;
    ds *= ds;
  }
  if (lane == 63) wtot[wv] = I;
  __syncthreads();
  float carry = 0.f;
  for (int w2 = 0; w2 < wv; ++w2) carry = carry * ds + wtot[w2];
  float dlp1 = exp2f(log2f(d8) * (float)(lane + 1));
  float Ig = I + dlp1 * carry;
  float E = __shfl_up(Ig, 1, 64);
  if (lane == 0) E = carry;
  float S = E;
  float out[8];
#pragma unroll
  for (int i = 0; i < 8; ++i) {
    out[i] = S;
    S = d * (S + z[i]);
  }
  float4* wp = (float4*)(w + ((size_t)bh * 36 + ch) * 2048 + t0);
  wp[0] = make_float4(out[0], out[1], out[2], out[3]);
  wp[1] = make_float4(out[4], out[5], out[6], out[7]);
}

// ---- scandot + per-h gate term: a[bh][t] = sig(score*scale_h) * sig(memg logit) ----
__global__ __launch_bounds__(256) void k_scandot(const float* __restrict__ rr,
                                                 const float* __restrict__ w,
                                                 const float* __restrict__ Cs,
                                                 const float* __restrict__ memg_b,
                                                 const float* __restrict__ mem_scale,
                                                 float* __restrict__ aout) {
  const int bh = blockIdx.y;
  const int b = bh >> 4, h = bh & 15;
  const int t = blockIdx.x * 256 + threadIdx.x;
  const float* rb = rr + ((size_t)bh * 2048 + t) * 6;
  float r[6];
#pragma unroll
  for (int i = 0; i < 6; ++i) r[i] = rb[i];
  const float* wb = w + (size_t)bh * 36 * 2048 + t;
  float s = 0.f;
#pragma unroll
  for (int ch = 0; ch < 36; ++ch)
    s += r[ch / 6] * r[ch % 6] * wb[(size_t)ch * 2048];
  float gl = Cs[(size_t)(b * 2048 + t) * 272 + 256 + h] + memg_b[h];
  float a = 1.f / (1.f + __expf(-s * mem_scale[h]));
  float gg = 1.f / (1.f + __expf(-gl));
  aout[(size_t)bh * 2048 + t] = a * gg;
}

// ---------------- gate: gmean[b,t] = mean_h a[bh][t] ----------------
__global__ __launch_bounds__(256) void k_gate(const float* __restrict__ aout,
                                              float* __restrict__ gmean) {
  int idx = blockIdx.x * 256 + threadIdx.x;
  if (idx >= BT) return;
  int b = idx >> 11, t = idx & 2047;
  float acc = 0.f;
#pragma unroll
  for (int h = 0; h < 16; ++h)
    acc += aout[((size_t)(b * 16 + h) * 2048) + t];
  gmean[idx] = acc * (1.f / 16.f);
}

extern "C" void kernel_launch(void* const* d_in, const int* in_sizes, int n_in,
                              void* d_out, int out_size, void* d_ws, size_t ws_size,
                              hipStream_t stream) {
  const float* x = (const float*)d_in[0];
  const float* qkv_w = (const float*)d_in[1];
  const float* qkv_b = (const float*)d_in[2];
  const float* w1w = (const float*)d_in[3];
  const float* w2w = (const float*)d_in[4];
  const float* w1r = (const float*)d_in[5];
  const float* w2r = (const float*)d_in[6];
  const float* memv_w = (const float*)d_in[7];
  const float* memv_b = (const float*)d_in[8];
  const float* memg_w = (const float*)d_in[9];
  const float* memg_b = (const float*)d_in[10];
  const float* mem_scale = (const float*)d_in[11];
  const float* out_w = (const float*)d_in[12];
  const float* out_b = (const float*)d_in[13];
  const float* Jm = (const float*)d_in[14];
  const float* decays = (const float*)d_in[15];

  char* w = (char*)d_ws;
  size_t off = 0;
  auto alloc = [&](size_t bytes) -> void* {
    void* p = w + off;
    off += (bytes + 255) & ~(size_t)255;
    return p;
  };
  short* xb = (short*)alloc((size_t)BT * Dd * 2);
  short* WTall = (short*)alloc((size_t)4480 * 1024 * 2);  // qkv|memv|sm
  short* WTout = (short*)alloc((size_t)1024 * 1024 * 2);
  short* qb = (short*)alloc((size_t)32 * 2048 * 64 * 2);
  short* kb = (short*)alloc((size_t)32 * 2048 * 64 * 2);
  short* vtmp = (short*)alloc((size_t)BT * 1024 * 2);
  short* vb = (short*)alloc((size_t)32 * 64 * 2048 * 2);
  float* Csm = (float*)alloc((size_t)BT * 272 * 4);
  float* ua = (float*)alloc((size_t)32 * 2048 * 6 * 4);
  float* ra = (float*)alloc((size_t)32 * 2048 * 6 * 4);
  float* sc = (float*)alloc((size_t)32 * 2048 * 4);
  float* gm = (float*)alloc((size_t)BT * 4);
  short* mvb = (short*)alloc((size_t)BT * 1024 * 2);
  short* Fb = (short*)alloc((size_t)BT * Dd * 2);
  float* wscan = (float*)alloc((size_t)32 * 36 * 2048 * 4);
  (void)ws_size; (void)in_sizes; (void)n_in; (void)out_size;

  // prep: all weight transposes + x->bf16 in ONE launch
  k_wtall<<<5456, 256, 0, stream>>>(qkv_w, memv_w, out_w, w1w, w2w, w1r, w2r,
                                    memg_w, WTall, WTout, x, xb);

  // fused GEMM: qkv (q pre-scaled) | memv->bf16 | sm->Csm over N=4480, 4 blocks/CU
  k_g128<<<1120, 256, 0, stream>>>(xb, WTall, qkv_b, memv_b,
                                   qb, kb, vtmp, mvb, Csm, 1024);

  // lines (256 blocks) || vtrans (1024 blocks) in one launch
  k_lv<<<1280, 256, 0, stream>>>(Csm, Jm, ua, ra, vtmp, vb);

  // decay scan + scandot(+per-h gate term) + 16-mean
  k_scanw<<<dim3(36, 32), 256, 0, stream>>>(ua, wscan, decays);
  k_scandot<<<dim3(8, 32), 256, 0, stream>>>(ra, wscan, Csm, memg_b, mem_scale, sc);
  k_gate<<<(BT + 255) / 256, 256, 0, stream>>>(sc, gm);

  // attention (epilogue fuses + gm*mvb -> Fb): 1024 blocks, 4/CU, quad-balanced
  k_attn<<<1024, 256, 0, stream>>>(qb, kb, vb, mvb, gm, Fb);

  // final GEMM: 64x64-tile full-K, fp32 + bias -> d_out, grid 1024 (4/CU)
  k_gout<<<1024, 256, 0, stream>>>(Fb, WTout, out_b, (float*)d_out, 1024);
}